// Round 11
// baseline (352.510 us; speedup 1.0000x reference)
//
#include <hip/hip_runtime.h>
#include <hip/hip_fp16.h>

#define NODES 50000
#define EDGES 800000
#define HID   128
#define HEADS 4
// DK = 32, scale = 1/sqrt(32)
#define SCORE_SCALE 0.17677669529663687f

#define NBUCK ((NODES + 255) >> 8)   // 196 buckets of 256 src nodes
#define CHUNK 4096

#define NSLICE 4                      // 32-dim slices; slice row = 64B

typedef unsigned int       u32;
typedef unsigned short     u16;
typedef unsigned long long u64;

typedef __attribute__((ext_vector_type(8))) short bf16x8;
typedef __attribute__((ext_vector_type(4))) float f32x4;

// round-to-nearest-even f32 -> bf16
__device__ __forceinline__ u16 f2bf(float f) {
    u32 u = __builtin_bit_cast(u32, f);
    return (u16)((u + 0x7FFFu + ((u >> 16) & 1u)) >> 16);
}
__device__ __forceinline__ float bflo(u32 u) { return __builtin_bit_cast(float, u << 16); }
__device__ __forceinline__ float bfhi(u32 u) { return __builtin_bit_cast(float, u & 0xFFFF0000u); }
__device__ __forceinline__ float bdot2(u32 a, u32 b) {
    return bflo(a) * bflo(b) + bfhi(a) * bfhi(b);
}
// fp16 pair <-> f32 pair
__device__ __forceinline__ float2 h2f2(u32 u) {
    __half2 h = __builtin_bit_cast(__half2, u);
    return __half22float2(h);
}
__device__ __forceinline__ u32 f2h2(float a, float b) {
    __half2 h = __floats2half2_rn(a, b);
    return __builtin_bit_cast(u32, h);
}

// ---------------------------------------------------------------------------
// W prep: Wt[n][k] = bf16(W[k][n]), both 128x128. 2 matrices.
// ---------------------------------------------------------------------------
__global__ __launch_bounds__(256) void wprep(
    const float* __restrict__ Wq, const float* __restrict__ Wk,
    u16* __restrict__ Wqt, u16* __restrict__ Wkt)
{
    int e   = blockIdx.x * 256 + threadIdx.x;
    int mat = e >> 14;
    int idx = e & 16383;
    int k  = idx >> 7;
    int nn = idx & 127;
    const float* W = mat ? Wk : Wq;
    u16*        Wt = mat ? Wkt : Wqt;
    Wt[nn * 128 + k] = f2bf(W[idx]);
}

// ---------------------------------------------------------------------------
// MFMA Q/K projection. Wave = one 16-row tile, both matrices.
// Emits fp16 copy of x in SLICED layout: xh[(slice*N + row)*32 + d32]
// (formula identical to round-4's PASSED quarter-major write).
// ---------------------------------------------------------------------------
__global__ __launch_bounds__(256) void gemm_qk_mfma(
    const float* __restrict__ x,
    const u16* __restrict__ Wqt, const float* __restrict__ bq,
    const u16* __restrict__ Wkt, const float* __restrict__ bk,
    u16* __restrict__ qb, u16* __restrict__ kb, u16* __restrict__ xh, int n)
{
    const int l  = threadIdx.x & 63;
    const int w  = threadIdx.x >> 6;
    const int lr = l & 15;
    const int kg = l >> 4;

    const int arow   = blockIdx.x * 64 + w * 16 + lr;
    const bool av    = (arow < n);
    const int  arowc = av ? arow : (n - 1);

    bf16x8 afrag[4];
    #pragma unroll
    for (int ks = 0; ks < 4; ++ks) {
        const float* px = x + (size_t)arowc * HID + ks * 32 + kg * 8;
        float4 p0 = *(const float4*)px;
        float4 p1 = *(const float4*)(px + 4);
        uint4 pk;
        pk.x = (u32)f2bf(p0.x) | ((u32)f2bf(p0.y) << 16);
        pk.y = (u32)f2bf(p0.z) | ((u32)f2bf(p0.w) << 16);
        pk.z = (u32)f2bf(p1.x) | ((u32)f2bf(p1.y) << 16);
        pk.w = (u32)f2bf(p1.z) | ((u32)f2bf(p1.w) << 16);
        afrag[ks] = __builtin_bit_cast(bf16x8, pk);
        if (av) {
            uint4 ph;
            ph.x = f2h2(p0.x, p0.y);
            ph.y = f2h2(p0.z, p0.w);
            ph.z = f2h2(p1.x, p1.y);
            ph.w = f2h2(p1.z, p1.w);
            // sliced: slice = ks, 32 dims per slice
            *(uint4*)(xh + ((size_t)ks * n + arow) * 32 + kg * 8) = ph;
        }
    }

    #pragma unroll
    for (int mat = 0; mat < 2; ++mat) {
        const u16*   Wt   = mat ? Wkt : Wqt;
        const float* bias = mat ? bk : bq;
        u16*         outp = mat ? kb : qb;

        #pragma unroll
        for (int cb = 0; cb < 8; ++cb) {
            float bc = bias[cb * 16 + lr];
            f32x4 acc = {bc, bc, bc, bc};
            #pragma unroll
            for (int ks = 0; ks < 4; ++ks) {
                bf16x8 bfrag = __builtin_bit_cast(bf16x8,
                    *(const uint4*)(Wt + (size_t)(cb * 16 + lr) * 128 + ks * 32 + kg * 8));
                acc = __builtin_amdgcn_mfma_f32_16x16x32_bf16(afrag[ks], bfrag, acc, 0, 0, 0);
            }
            #pragma unroll
            for (int reg = 0; reg < 4; ++reg) {
                int gr = blockIdx.x * 64 + w * 16 + kg * 4 + reg;
                if (gr < n) outp[(size_t)gr * HID + cb * 16 + lr] = f2bf(acc[reg]);
            }
        }
    }
}

// ---------------------------------------------------------------------------
// out-degree histogram over src
// ---------------------------------------------------------------------------
__global__ __launch_bounds__(256) void hist_kernel(
    const int* __restrict__ ei, int* __restrict__ deg)
{
    int i = blockIdx.x * 256 + threadIdx.x;
    if (i < EDGES) atomicAdd(&deg[ei[i]], 1);
}

// ---------------------------------------------------------------------------
// two-level exclusive scan of deg -> off; also emits bucket cursors
// ---------------------------------------------------------------------------
__global__ __launch_bounds__(1024) void scan1(
    const int* __restrict__ deg, int* __restrict__ off,
    int* __restrict__ part, int n)
{
    __shared__ int sd[1024];
    int t = threadIdx.x, i = blockIdx.x * 1024 + t;
    int v = (i < n) ? deg[i] : 0;
    sd[t] = v;
    __syncthreads();
    #pragma unroll
    for (int o = 1; o < 1024; o <<= 1) {
        int a = (t >= o) ? sd[t - o] : 0;
        __syncthreads();
        sd[t] += a;
        __syncthreads();
    }
    if (i < n) off[i] = sd[t] - v;
    if (t == 1023) part[blockIdx.x] = sd[1023];
}

__global__ __launch_bounds__(64) void scan2(int* __restrict__ part,
                                            int* __restrict__ off_n, int nb)
{
    int t = threadIdx.x;
    int v = (t < nb) ? part[t] : 0;
    int orig = v;
    #pragma unroll
    for (int o = 1; o < 64; o <<= 1) {
        int a = __shfl_up(v, o);
        if (t >= o) v += a;
    }
    if (t < nb) part[t] = v - orig;
    if (t == 63) *off_n = v;
}

__global__ __launch_bounds__(1024) void scan3(
    int* __restrict__ off, int* __restrict__ bcur,
    const int* __restrict__ part, int n)
{
    int i = blockIdx.x * 1024 + threadIdx.x;
    if (i < n) {
        int o = off[i] + part[blockIdx.x];
        off[i] = o;
        if ((i & 255) == 0) bcur[i >> 8] = o;   // bucket base cursor
    }
}

// ---------------------------------------------------------------------------
// Phase 1: bin edges by bucket (src>>8) into tmp, bucket-contiguous.
// ---------------------------------------------------------------------------
__global__ __launch_bounds__(256) void bin_edges(
    const int* __restrict__ ei, int* __restrict__ bcur, u32* __restrict__ tmp)
{
    __shared__ u32 buf[CHUNK];
    __shared__ int hist[NBUCK];
    __shared__ int lcur[NBUCK];

    const int t  = threadIdx.x;
    const int e0 = blockIdx.x * CHUNK;
    const int e1 = (e0 + CHUNK < EDGES) ? e0 + CHUNK : EDGES;
    const int cnt = e1 - e0;

    for (int b = t; b < NBUCK; b += 256) hist[b] = 0;
    __syncthreads();

    for (int i = t; i < cnt; i += 256) {
        int src = ei[e0 + i];
        int dst = ei[EDGES + e0 + i];
        buf[i] = (u32)dst | ((u32)(src & 255) << 16) | ((u32)(src >> 8) << 24);
        atomicAdd(&hist[src >> 8], 1);
    }
    __syncthreads();

    for (int b = t; b < NBUCK; b += 256) {
        int h = hist[b];
        lcur[b] = h ? atomicAdd(&bcur[b], h) : 0;
    }
    __syncthreads();

    for (int i = t; i < cnt; i += 256) {
        u32 pk  = buf[i];
        int b   = pk >> 24;
        int pos = atomicAdd(&lcur[b], 1);
        tmp[pos] = pk & 0x00FFFFFFu;          // srcLocal<<16 | dst
    }
}

// ---------------------------------------------------------------------------
// Phase 2: exact CSR placement within each bucket (LDS cursors, local window)
// ---------------------------------------------------------------------------
__global__ __launch_bounds__(256) void place_edges(
    const u32* __restrict__ tmp, const int* __restrict__ off,
    u32* __restrict__ epack, int n)
{
    __shared__ int lcur[256];
    const int t     = threadIdx.x;
    const int nbase = blockIdx.x << 8;
    const int nend  = (nbase + 256 < n) ? nbase + 256 : n;

    if (nbase + t < nend) lcur[t] = off[nbase + t];
    __syncthreads();

    const int s0 = off[nbase];
    const int s1 = off[nend];
    for (int i = s0 + t; i < s1; i += 256) {
        u32 pk    = tmp[i];
        int local = pk >> 16;
        int pos   = atomicAdd(&lcur[local], 1);
        epack[pos] = pk & 0xFFFFu;            // dst only (att packed later)
    }
}

// ---------------------------------------------------------------------------
// CSR-ordered scores: wave per src node, 4 groups x 16 lanes, 4-deep gather
// pipelining per group. q[src] loaded once. e-values stored packed bf16.
// ---------------------------------------------------------------------------
__global__ __launch_bounds__(256) void score_csr(
    const u16* __restrict__ qb, const u16* __restrict__ kb,
    const int* __restrict__ off, const u32* __restrict__ ccol,
    u16* __restrict__ evals16, float* __restrict__ nsum, int n)
{
    const int wv   = (blockIdx.x * 256 + threadIdx.x) >> 6;   // src node
    const int lane = threadIdx.x & 63;
    const int l16  = lane & 15;
    const int grp  = lane >> 4;
    if (wv >= n) return;

    const int beg = off[wv];
    const int end = off[wv + 1];

    uint4 qv = *(const uint4*)(qb + (size_t)wv * HID + l16 * 8);

    for (int j = beg; j < end; j += 16) {
        u32 d[4]; uint4 kv[4];
        #pragma unroll
        for (int u = 0; u < 4; ++u) {
            int e  = j + grp + u * 4;
            int ec = (e < end) ? e : (end - 1);
            d[u] = ccol[ec];
        }
        #pragma unroll
        for (int u = 0; u < 4; ++u)
            kv[u] = *(const uint4*)(kb + (size_t)d[u] * HID + l16 * 8);
        #pragma unroll
        for (int u = 0; u < 4; ++u) {
            int e = j + grp + u * 4;
            float p = bdot2(qv.x, kv[u].x) + bdot2(qv.y, kv[u].y) +
                      bdot2(qv.z, kv[u].z) + bdot2(qv.w, kv[u].w);
            p += __shfl_xor(p, 1);
            p += __shfl_xor(p, 2);
            if (e < end && (l16 & 3) == 0) {
                int head = l16 >> 2;
                float ev = __expf(p * SCORE_SCALE);
                evals16[(size_t)e * HEADS + head] = f2bf(ev);
                atomicAdd(&nsum[(size_t)d[u] * HEADS + head], ev);
            }
        }
    }
}

// ---------------------------------------------------------------------------
// head-mean attention; packs epack[pos] = dst | bf16(att)<<16 IN PLACE.
// ---------------------------------------------------------------------------
__global__ __launch_bounds__(256) void finalize_kernel(
    const u16* __restrict__ evals16, const float* __restrict__ nsum,
    u32* __restrict__ epack)
{
    int pos = blockIdx.x * 256 + threadIdx.x;
    if (pos >= EDGES) return;
    u32 dst = epack[pos];
    u64 ev8 = *(const u64*)(evals16 + (size_t)pos * HEADS);
    u32 lo = (u32)ev8, hi = (u32)(ev8 >> 32);
    float4 sv = *(const float4*)(nsum + (size_t)dst * HEADS);
    float am = 0.25f * (bflo(lo) / (sv.x + 1e-16f) + bfhi(lo) / (sv.y + 1e-16f) +
                        bflo(hi) / (sv.z + 1e-16f) + bfhi(hi) / (sv.w + 1e-16f));
    epack[pos] = dst | ((u32)f2bf(am) << 16);
}

// ---------------------------------------------------------------------------
// XCD-SLICED Euler step, GROUP-PER-NODE (round-4-proven inner loop; no
// cross-group reduce -- r10's shfl_xor combine was the correctness suspect).
// State fp16 in 4 column-slices of 32 dims: z[(slice*N + node)*32 + d].
// slice = blockIdx%4: with round-robin blockIdx->XCD dispatch each XCD's
// 4MB L2 holds exactly its 3.2MB slice. Block = 16 groups of 16 lanes; each
// group owns one node, iterates its edges 8-deep, lanes cover the 32 dims
// (one u32 = 2 dims per lane). Shfl sources stay within the group (grpb).
// NOTE (r7): keep wave count high, no persistence. (r4): no phase loop.
// ---------------------------------------------------------------------------
template<int FINAL>
__global__ __launch_bounds__(256) void spmv_x(
    const u16* __restrict__ inh, u16* __restrict__ outh,
    float* __restrict__ outf,
    const int* __restrict__ off, const u32* __restrict__ epack, int n)
{
    const int tid   = threadIdx.x;
    const int l16   = tid & 15;
    const int grpb  = tid & 48;                      // group base lane in wave
    const int slice = blockIdx.x & 3;
    const int w     = (blockIdx.x >> 2) * 16 + (tid >> 4);   // node (exact)

    const u32* inq = (const u32*)(inh + (size_t)slice * n * 32);  // 16 u32/row

    const int beg = off[w];
    const int end = off[w + 1];

    float ax = 0.f, ay = 0.f;
    for (int j = beg; j < end; j += 16) {
        int cnt = end - j; if (cnt > 16) cnt = 16;
        u32 e = 0;
        if (l16 < cnt) e = __builtin_nontemporal_load(epack + j + l16);

        int jj = 0;
        for (; jj + 8 <= cnt; jj += 8) {
            u32 ee[8], s[8];
            #pragma unroll
            for (int u = 0; u < 8; ++u) ee[u] = __shfl(e, grpb + jj + u);
            #pragma unroll
            for (int u = 0; u < 8; ++u)
                s[u] = inq[(size_t)(ee[u] & 0xFFFFu) * 16 + l16];
            #pragma unroll
            for (int u = 0; u < 8; ++u) {
                float vv = bfhi(ee[u]);
                float2 sv = h2f2(s[u]);
                ax += vv * sv.x;
                ay += vv * sv.y;
            }
        }
        for (; jj + 4 <= cnt; jj += 4) {
            u32 ee[4], s[4];
            #pragma unroll
            for (int u = 0; u < 4; ++u) ee[u] = __shfl(e, grpb + jj + u);
            #pragma unroll
            for (int u = 0; u < 4; ++u)
                s[u] = inq[(size_t)(ee[u] & 0xFFFFu) * 16 + l16];
            #pragma unroll
            for (int u = 0; u < 4; ++u) {
                float vv = bfhi(ee[u]);
                float2 sv = h2f2(s[u]);
                ax += vv * sv.x;
                ay += vv * sv.y;
            }
        }
        for (; jj < cnt; ++jj) {
            u32 ee = __shfl(e, grpb + jj);
            u32 s  = inq[(size_t)(ee & 0xFFFFu) * 16 + l16];
            float vv = bfhi(ee);
            float2 sv = h2f2(s);
            ax += vv * sv.x;
            ay += vv * sv.y;
        }
    }

    // own-row slice (64B line)
    u32 zi = inq[(size_t)w * 16 + l16];
    float2 xi = h2f2(zi);
    const float ox = 0.75f * xi.x + 0.25f * ax;
    const float oy = 0.75f * xi.y + 0.25f * ay;

    if (FINAL) {
        float2 o; o.x = ox; o.y = oy;
        __builtin_nontemporal_store(__builtin_bit_cast(u64, o),
            (u64*)(outf + (size_t)w * HID + slice * 32 + l16 * 2));
    } else {
        __builtin_nontemporal_store(f2h2(ox, oy),
            (u32*)outh + ((size_t)slice * n + w) * 16 + l16);
    }
}

// ---------------------------------------------------------------------------
extern "C" void kernel_launch(void* const* d_in, const int* in_sizes, int n_in,
                              void* d_out, int out_size, void* d_ws, size_t ws_size,
                              hipStream_t stream)
{
    (void)in_sizes; (void)n_in; (void)out_size; (void)ws_size;

    const float* x  = (const float*)d_in[0];
    const float* Wq = (const float*)d_in[1];
    const float* bq = (const float*)d_in[2];
    const float* Wk = (const float*)d_in[3];
    const float* bk = (const float*)d_in[4];
    const int*   ei = (const int*)d_in[5];
    float* out = (float*)d_out;

    const int N = NODES, E = EDGES;
    const size_t ROWB_B = (size_t)N * HID * 2;   // 12.8 MB 16-bit state

    char* ws = (char*)d_ws;
    // region A (25.6 MB): qb|kb -- dead after score_csr -- reused as z1|z2
    u16*   qb    = (u16*)(ws);
    u16*   kb    = (u16*)(ws + ROWB_B);
    u16*   z1    = (u16*)(ws);
    u16*   z2    = (u16*)(ws + ROWB_B);
    ws += 2 * ROWB_B;
    // xh: sliced fp16 copy of x, live through euler step 1
    u16*   xh    = (u16*)ws;  ws += ROWB_B;
    // evals16 (6.4 MB used) -- dead after finalize -- region reused as z3
    u16*   evals16 = (u16*)ws;
    u16*   z3    = (u16*)ws;  ws += (size_t)E * HEADS * 4;   // 12.8 MB region
    float* nsum  = (float*)ws; ws += (size_t)N * HEADS * 4;
    int*   deg   = (int*)ws;   ws += (size_t)N * 4;
    int*   off   = (int*)ws;   ws += ((size_t)(N + 1) * 4 + 255) & ~255ull;
    int*   bcur  = (int*)ws;   ws += ((size_t)NBUCK * 4 + 255) & ~255ull;
    int*   part  = (int*)ws;   ws += 256;
    u32*   epack = (u32*)ws;   ws += (size_t)E * 4;   // dst-only CSR, then packed
    u32*   tmp   = (u32*)ws;   ws += (size_t)E * 4;   // bucket-grouped edges
    u16*   Wqt   = (u16*)ws;   ws += (size_t)128 * 128 * 2;
    u16*   Wkt   = (u16*)ws;   ws += (size_t)128 * 128 * 2;

    // zero nsum + deg (contiguous)
    hipMemsetAsync(nsum, 0, (size_t)N * HEADS * 4 + (size_t)N * 4, stream);

    // W -> bf16 transposed
    wprep<<<128, 256, 0, stream>>>(Wq, Wk, Wqt, Wkt);

    // Q/K projections via MFMA (bf16 out) + sliced fp16 copy of x
    gemm_qk_mfma<<<(N + 63) / 64, 256, 0, stream>>>(
        x, Wqt, bq, Wkt, bk, qb, kb, xh, N);

    // degree histogram (by src)
    hist_kernel<<<E / 256, 256, 0, stream>>>(ei, deg);

    // CSR offsets: two-level scan (+ bucket cursors)
    const int nb = (N + 1023) / 1024;
    scan1<<<nb, 1024, 0, stream>>>(deg, off, part, N);
    scan2<<<1, 64, 0, stream>>>(part, off + N, nb);
    scan3<<<nb, 1024, 0, stream>>>(off, bcur, part, N);

    // two-phase binned CSR fill
    bin_edges<<<(E + CHUNK - 1) / CHUNK, 256, 0, stream>>>(ei, bcur, tmp);
    place_edges<<<NBUCK, 256, 0, stream>>>(tmp, off, epack, N);

    // CSR-ordered scores -> exp (bf16) -> segment sums
    score_csr<<<(N * 64 + 255) / 256, 256, 0, stream>>>(
        qb, kb, off, epack, evals16, nsum, N);

    // attention mean, packed in place
    finalize_kernel<<<E / 256, 256, 0, stream>>>(evals16, nsum, epack);

    // 4 Euler steps, XCD-sliced fp16 chain: xh -> z1 -> z2 -> z3 -> out(f32)
    // grid: slice = blockIdx%4, 16 nodes per block (group-per-node)
    const int sgrid = NSLICE * ((N + 15) / 16);   // 4 * 3125 = 12500
    spmv_x<0><<<sgrid, 256, 0, stream>>>(xh, z1, nullptr, off, epack, N);
    spmv_x<0><<<sgrid, 256, 0, stream>>>(z1, z2, nullptr, off, epack, N);
    spmv_x<0><<<sgrid, 256, 0, stream>>>(z2, z3, nullptr, off, epack, N);
    spmv_x<1><<<sgrid, 256, 0, stream>>>(z3, nullptr, out, off, epack, N);
}

// Round 12
// 294.071 us; speedup vs baseline: 1.1987x; 1.1987x over previous
//
#include <hip/hip_runtime.h>
#include <hip/hip_fp16.h>

#define NODES 50000
#define EDGES 800000
#define HID   128
#define HEADS 4
// DK = 32, scale = 1/sqrt(32)
#define SCORE_SCALE 0.17677669529663687f

#define NBUCK ((NODES + 255) >> 8)   // 196 buckets of 256 src nodes
#define CHUNK 4096

typedef unsigned int       u32;
typedef unsigned short     u16;
typedef unsigned long long u64;

typedef __attribute__((ext_vector_type(8))) short bf16x8;
typedef __attribute__((ext_vector_type(4))) float f32x4;

// round-to-nearest-even f32 -> bf16
__device__ __forceinline__ u16 f2bf(float f) {
    u32 u = __builtin_bit_cast(u32, f);
    return (u16)((u + 0x7FFFu + ((u >> 16) & 1u)) >> 16);
}
__device__ __forceinline__ float bflo(u32 u) { return __builtin_bit_cast(float, u << 16); }
__device__ __forceinline__ float bfhi(u32 u) { return __builtin_bit_cast(float, u & 0xFFFF0000u); }
__device__ __forceinline__ float bdot2(u32 a, u32 b) {
    return bflo(a) * bflo(b) + bfhi(a) * bfhi(b);
}
// fp16 pair <-> f32 pair
__device__ __forceinline__ float2 h2f2(u32 u) {
    __half2 h = __builtin_bit_cast(__half2, u);
    return __half22float2(h);
}
__device__ __forceinline__ u32 f2h2(float a, float b) {
    __half2 h = __floats2half2_rn(a, b);
    return __builtin_bit_cast(u32, h);
}

// ---------------------------------------------------------------------------
// W prep: Wt[n][k] = bf16(W[k][n]), both 128x128. 2 matrices.
// ---------------------------------------------------------------------------
__global__ __launch_bounds__(256) void wprep(
    const float* __restrict__ Wq, const float* __restrict__ Wk,
    u16* __restrict__ Wqt, u16* __restrict__ Wkt)
{
    int e   = blockIdx.x * 256 + threadIdx.x;
    int mat = e >> 14;
    int idx = e & 16383;
    int k  = idx >> 7;
    int nn = idx & 127;
    const float* W = mat ? Wk : Wq;
    u16*        Wt = mat ? Wkt : Wqt;
    Wt[nn * 128 + k] = f2bf(W[idx]);
}

// ---------------------------------------------------------------------------
// MFMA Q/K projection. Wave = one 16-row tile, both matrices.
// Also emits row-major fp16 copy of x (xh) for the Euler gathers.
// ---------------------------------------------------------------------------
__global__ __launch_bounds__(256) void gemm_qk_mfma(
    const float* __restrict__ x,
    const u16* __restrict__ Wqt, const float* __restrict__ bq,
    const u16* __restrict__ Wkt, const float* __restrict__ bk,
    u16* __restrict__ qb, u16* __restrict__ kb, u16* __restrict__ xh, int n)
{
    const int l  = threadIdx.x & 63;
    const int w  = threadIdx.x >> 6;
    const int lr = l & 15;
    const int kg = l >> 4;

    const int arow   = blockIdx.x * 64 + w * 16 + lr;
    const bool av    = (arow < n);
    const int  arowc = av ? arow : (n - 1);

    bf16x8 afrag[4];
    #pragma unroll
    for (int ks = 0; ks < 4; ++ks) {
        const float* px = x + (size_t)arowc * HID + ks * 32 + kg * 8;
        float4 p0 = *(const float4*)px;
        float4 p1 = *(const float4*)(px + 4);
        uint4 pk;
        pk.x = (u32)f2bf(p0.x) | ((u32)f2bf(p0.y) << 16);
        pk.y = (u32)f2bf(p0.z) | ((u32)f2bf(p0.w) << 16);
        pk.z = (u32)f2bf(p1.x) | ((u32)f2bf(p1.y) << 16);
        pk.w = (u32)f2bf(p1.z) | ((u32)f2bf(p1.w) << 16);
        afrag[ks] = __builtin_bit_cast(bf16x8, pk);
        if (av) {
            uint4 ph;
            ph.x = f2h2(p0.x, p0.y);
            ph.y = f2h2(p0.z, p0.w);
            ph.z = f2h2(p1.x, p1.y);
            ph.w = f2h2(p1.z, p1.w);
            *(uint4*)(xh + (size_t)arow * HID + ks * 32 + kg * 8) = ph;
        }
    }

    #pragma unroll
    for (int mat = 0; mat < 2; ++mat) {
        const u16*   Wt   = mat ? Wkt : Wqt;
        const float* bias = mat ? bk : bq;
        u16*         outp = mat ? kb : qb;

        #pragma unroll
        for (int cb = 0; cb < 8; ++cb) {
            float bc = bias[cb * 16 + lr];
            f32x4 acc = {bc, bc, bc, bc};
            #pragma unroll
            for (int ks = 0; ks < 4; ++ks) {
                bf16x8 bfrag = __builtin_bit_cast(bf16x8,
                    *(const uint4*)(Wt + (size_t)(cb * 16 + lr) * 128 + ks * 32 + kg * 8));
                acc = __builtin_amdgcn_mfma_f32_16x16x32_bf16(afrag[ks], bfrag, acc, 0, 0, 0);
            }
            #pragma unroll
            for (int reg = 0; reg < 4; ++reg) {
                int gr = blockIdx.x * 64 + w * 16 + kg * 4 + reg;
                if (gr < n) outp[(size_t)gr * HID + cb * 16 + lr] = f2bf(acc[reg]);
            }
        }
    }
}

// ---------------------------------------------------------------------------
// out-degree histogram over src
// ---------------------------------------------------------------------------
__global__ __launch_bounds__(256) void hist_kernel(
    const int* __restrict__ ei, int* __restrict__ deg)
{
    int i = blockIdx.x * 256 + threadIdx.x;
    if (i < EDGES) atomicAdd(&deg[ei[i]], 1);
}

// ---------------------------------------------------------------------------
// two-level exclusive scan of deg -> off; also emits bucket cursors
// ---------------------------------------------------------------------------
__global__ __launch_bounds__(1024) void scan1(
    const int* __restrict__ deg, int* __restrict__ off,
    int* __restrict__ part, int n)
{
    __shared__ int sd[1024];
    int t = threadIdx.x, i = blockIdx.x * 1024 + t;
    int v = (i < n) ? deg[i] : 0;
    sd[t] = v;
    __syncthreads();
    #pragma unroll
    for (int o = 1; o < 1024; o <<= 1) {
        int a = (t >= o) ? sd[t - o] : 0;
        __syncthreads();
        sd[t] += a;
        __syncthreads();
    }
    if (i < n) off[i] = sd[t] - v;
    if (t == 1023) part[blockIdx.x] = sd[1023];
}

__global__ __launch_bounds__(64) void scan2(int* __restrict__ part,
                                            int* __restrict__ off_n, int nb)
{
    int t = threadIdx.x;
    int v = (t < nb) ? part[t] : 0;
    int orig = v;
    #pragma unroll
    for (int o = 1; o < 64; o <<= 1) {
        int a = __shfl_up(v, o);
        if (t >= o) v += a;
    }
    if (t < nb) part[t] = v - orig;
    if (t == 63) *off_n = v;
}

__global__ __launch_bounds__(1024) void scan3(
    int* __restrict__ off, int* __restrict__ bcur,
    const int* __restrict__ part, int n)
{
    int i = blockIdx.x * 1024 + threadIdx.x;
    if (i < n) {
        int o = off[i] + part[blockIdx.x];
        off[i] = o;
        if ((i & 255) == 0) bcur[i >> 8] = o;   // bucket base cursor
    }
}

// ---------------------------------------------------------------------------
// Phase 1: bin edges by bucket (src>>8) into tmp, bucket-contiguous.
// ---------------------------------------------------------------------------
__global__ __launch_bounds__(256) void bin_edges(
    const int* __restrict__ ei, int* __restrict__ bcur, u32* __restrict__ tmp)
{
    __shared__ u32 buf[CHUNK];
    __shared__ int hist[NBUCK];
    __shared__ int lcur[NBUCK];

    const int t  = threadIdx.x;
    const int e0 = blockIdx.x * CHUNK;
    const int e1 = (e0 + CHUNK < EDGES) ? e0 + CHUNK : EDGES;
    const int cnt = e1 - e0;

    for (int b = t; b < NBUCK; b += 256) hist[b] = 0;
    __syncthreads();

    for (int i = t; i < cnt; i += 256) {
        int src = ei[e0 + i];
        int dst = ei[EDGES + e0 + i];
        buf[i] = (u32)dst | ((u32)(src & 255) << 16) | ((u32)(src >> 8) << 24);
        atomicAdd(&hist[src >> 8], 1);
    }
    __syncthreads();

    for (int b = t; b < NBUCK; b += 256) {
        int h = hist[b];
        lcur[b] = h ? atomicAdd(&bcur[b], h) : 0;
    }
    __syncthreads();

    for (int i = t; i < cnt; i += 256) {
        u32 pk  = buf[i];
        int b   = pk >> 24;
        int pos = atomicAdd(&lcur[b], 1);
        tmp[pos] = pk & 0x00FFFFFFu;          // srcLocal<<16 | dst
    }
}

// ---------------------------------------------------------------------------
// Phase 2: exact CSR placement within each bucket (LDS cursors, local window)
// ---------------------------------------------------------------------------
__global__ __launch_bounds__(256) void place_edges(
    const u32* __restrict__ tmp, const int* __restrict__ off,
    u32* __restrict__ epack, int n)
{
    __shared__ int lcur[256];
    const int t     = threadIdx.x;
    const int nbase = blockIdx.x << 8;
    const int nend  = (nbase + 256 < n) ? nbase + 256 : n;

    if (nbase + t < nend) lcur[t] = off[nbase + t];
    __syncthreads();

    const int s0 = off[nbase];
    const int s1 = off[nend];
    for (int i = s0 + t; i < s1; i += 256) {
        u32 pk    = tmp[i];
        int local = pk >> 16;
        int pos   = atomicAdd(&lcur[local], 1);
        epack[pos] = pk & 0xFFFFu;            // dst only (att packed later)
    }
}

// ---------------------------------------------------------------------------
// CSR-ordered scores: wave per src node, 4 groups x 16 lanes, 8-deep gather
// pipelining per group (32 k-rows in flight per wave). q[src] loaded once.
// e-values stored packed bf16.
// ---------------------------------------------------------------------------
__global__ __launch_bounds__(256) void score_csr(
    const u16* __restrict__ qb, const u16* __restrict__ kb,
    const int* __restrict__ off, const u32* __restrict__ ccol,
    u16* __restrict__ evals16, float* __restrict__ nsum, int n)
{
    const int wv   = (blockIdx.x * 256 + threadIdx.x) >> 6;   // src node
    const int lane = threadIdx.x & 63;
    const int l16  = lane & 15;
    const int grp  = lane >> 4;
    if (wv >= n) return;

    const int beg = off[wv];
    const int end = off[wv + 1];

    uint4 qv = *(const uint4*)(qb + (size_t)wv * HID + l16 * 8);

    for (int j = beg; j < end; j += 32) {
        u32 d[8]; uint4 kv[8];
        #pragma unroll
        for (int u = 0; u < 8; ++u) {
            int e  = j + grp + u * 4;
            int ec = (e < end) ? e : (end - 1);
            d[u] = ccol[ec];
        }
        #pragma unroll
        for (int u = 0; u < 8; ++u)
            kv[u] = *(const uint4*)(kb + (size_t)d[u] * HID + l16 * 8);
        #pragma unroll
        for (int u = 0; u < 8; ++u) {
            int e = j + grp + u * 4;
            float p = bdot2(qv.x, kv[u].x) + bdot2(qv.y, kv[u].y) +
                      bdot2(qv.z, kv[u].z) + bdot2(qv.w, kv[u].w);
            p += __shfl_xor(p, 1);
            p += __shfl_xor(p, 2);
            if (e < end && (l16 & 3) == 0) {
                int head = l16 >> 2;
                float ev = __expf(p * SCORE_SCALE);
                evals16[(size_t)e * HEADS + head] = f2bf(ev);
                atomicAdd(&nsum[(size_t)d[u] * HEADS + head], ev);
            }
        }
    }
}

// ---------------------------------------------------------------------------
// head-mean attention; packs epack[pos] = dst | bf16(att)<<16 IN PLACE.
// ---------------------------------------------------------------------------
__global__ __launch_bounds__(256) void finalize_kernel(
    const u16* __restrict__ evals16, const float* __restrict__ nsum,
    u32* __restrict__ epack)
{
    int pos = blockIdx.x * 256 + threadIdx.x;
    if (pos >= EDGES) return;
    u32 dst = epack[pos];
    u64 ev8 = *(const u64*)(evals16 + (size_t)pos * HEADS);
    u32 lo = (u32)ev8, hi = (u32)(ev8 >> 32);
    float4 sv = *(const float4*)(nsum + (size_t)dst * HEADS);
    float am = 0.25f * (bflo(lo) / (sv.x + 1e-16f) + bfhi(lo) / (sv.y + 1e-16f) +
                        bflo(hi) / (sv.z + 1e-16f) + bfhi(hi) / (sv.w + 1e-16f));
    epack[pos] = dst | ((u32)f2bf(am) << 16);
}

// ---------------------------------------------------------------------------
// Euler step, fp16 state: out[i,:] = 0.75*in[i,:] + 0.25*sum att[j]*in[dst,:]
// Single fp16 buffer per step; final step writes f32 out.
// Wave per node; 16-deep batched gathers (r11 showed passes are latency/MLP-
// bound, not traffic-bound: FETCH 84->25 MB left dur unchanged).
// NOTE (r7): keep wave count high; no LDS-residency tricks.
// ---------------------------------------------------------------------------
template<int FINAL>
__global__ __launch_bounds__(256) void spmv_h(
    const u16* __restrict__ inh, u16* __restrict__ outh,
    float* __restrict__ outf,
    const int* __restrict__ off, const u32* __restrict__ epack, int n)
{
    const int w    = (blockIdx.x * 256 + threadIdx.x) >> 6;
    const int lane = threadIdx.x & 63;
    if (w >= n) return;

    const int beg = off[w];
    const int end = off[w + 1];

    float ax = 0.f, ay = 0.f;
    for (int j = beg; j < end; j += 64) {
        int cnt = end - j; if (cnt > 64) cnt = 64;
        u32 e = 0;
        if (lane < cnt) e = epack[j + lane];

        int jj = 0;
        for (; jj + 16 <= cnt; jj += 16) {
            u32 ee[16], s[16];
            #pragma unroll
            for (int u = 0; u < 16; ++u) ee[u] = __shfl(e, jj + u);
            #pragma unroll
            for (int u = 0; u < 16; ++u)
                s[u] = *(const u32*)(inh + (size_t)(ee[u] & 0xFFFFu) * HID + lane * 2);
            #pragma unroll
            for (int u = 0; u < 16; ++u) {
                float vv = bfhi(ee[u]);
                float2 sv = h2f2(s[u]);
                ax += vv * sv.x;
                ay += vv * sv.y;
            }
        }
        for (; jj + 8 <= cnt; jj += 8) {
            u32 ee[8], s[8];
            #pragma unroll
            for (int u = 0; u < 8; ++u) ee[u] = __shfl(e, jj + u);
            #pragma unroll
            for (int u = 0; u < 8; ++u)
                s[u] = *(const u32*)(inh + (size_t)(ee[u] & 0xFFFFu) * HID + lane * 2);
            #pragma unroll
            for (int u = 0; u < 8; ++u) {
                float vv = bfhi(ee[u]);
                float2 sv = h2f2(s[u]);
                ax += vv * sv.x;
                ay += vv * sv.y;
            }
        }
        for (; jj + 4 <= cnt; jj += 4) {
            u32 ee[4], s[4];
            #pragma unroll
            for (int u = 0; u < 4; ++u) ee[u] = __shfl(e, jj + u);
            #pragma unroll
            for (int u = 0; u < 4; ++u)
                s[u] = *(const u32*)(inh + (size_t)(ee[u] & 0xFFFFu) * HID + lane * 2);
            #pragma unroll
            for (int u = 0; u < 4; ++u) {
                float vv = bfhi(ee[u]);
                float2 sv = h2f2(s[u]);
                ax += vv * sv.x;
                ay += vv * sv.y;
            }
        }
        for (; jj < cnt; ++jj) {
            u32 ee = __shfl(e, jj);
            u32 s  = *(const u32*)(inh + (size_t)(ee & 0xFFFFu) * HID + lane * 2);
            float vv = bfhi(ee);
            float2 sv = h2f2(s);
            ax += vv * sv.x;
            ay += vv * sv.y;
        }
    }

    u32 zi = *(const u32*)(inh + (size_t)w * HID + lane * 2);
    float2 xi = h2f2(zi);
    const float ox = 0.75f * xi.x + 0.25f * ax;
    const float oy = 0.75f * xi.y + 0.25f * ay;
    if (FINAL) {
        float2 o; o.x = ox; o.y = oy;
        *(float2*)(outf + (size_t)w * HID + lane * 2) = o;
    } else {
        *(u32*)(outh + (size_t)w * HID + lane * 2) = f2h2(ox, oy);
    }
}

// ---------------------------------------------------------------------------
extern "C" void kernel_launch(void* const* d_in, const int* in_sizes, int n_in,
                              void* d_out, int out_size, void* d_ws, size_t ws_size,
                              hipStream_t stream)
{
    (void)in_sizes; (void)n_in; (void)out_size; (void)ws_size;

    const float* x  = (const float*)d_in[0];
    const float* Wq = (const float*)d_in[1];
    const float* bq = (const float*)d_in[2];
    const float* Wk = (const float*)d_in[3];
    const float* bk = (const float*)d_in[4];
    const int*   ei = (const int*)d_in[5];
    float* out = (float*)d_out;

    const int N = NODES, E = EDGES;
    const size_t ROWB_B = (size_t)N * HID * 2;   // 12.8 MB 16-bit state

    char* ws = (char*)d_ws;
    // region A (25.6 MB): qb|kb -- dead after score_csr -- reused as z1|z2
    u16*   qb    = (u16*)(ws);
    u16*   kb    = (u16*)(ws + ROWB_B);
    u16*   z1    = (u16*)(ws);
    u16*   z2    = (u16*)(ws + ROWB_B);
    ws += 2 * ROWB_B;
    // xh: fp16 copy of x, live through euler step 1
    u16*   xh    = (u16*)ws;  ws += ROWB_B;
    // evals16 (6.4 MB used) -- dead after finalize -- region reused as z3
    u16*   evals16 = (u16*)ws;
    u16*   z3    = (u16*)ws;  ws += (size_t)E * HEADS * 4;   // 12.8 MB region
    float* nsum  = (float*)ws; ws += (size_t)N * HEADS * 4;
    int*   deg   = (int*)ws;   ws += (size_t)N * 4;
    int*   off   = (int*)ws;   ws += ((size_t)(N + 1) * 4 + 255) & ~255ull;
    int*   bcur  = (int*)ws;   ws += ((size_t)NBUCK * 4 + 255) & ~255ull;
    int*   part  = (int*)ws;   ws += 256;
    u32*   epack = (u32*)ws;   ws += (size_t)E * 4;   // dst-only CSR, then packed
    u32*   tmp   = (u32*)ws;   ws += (size_t)E * 4;   // bucket-grouped edges
    u16*   Wqt   = (u16*)ws;   ws += (size_t)128 * 128 * 2;
    u16*   Wkt   = (u16*)ws;   ws += (size_t)128 * 128 * 2;

    // zero nsum + deg (contiguous)
    hipMemsetAsync(nsum, 0, (size_t)N * HEADS * 4 + (size_t)N * 4, stream);

    // W -> bf16 transposed
    wprep<<<128, 256, 0, stream>>>(Wq, Wk, Wqt, Wkt);

    // Q/K projections via MFMA (bf16 out) + fp16 copy of x
    gemm_qk_mfma<<<(N + 63) / 64, 256, 0, stream>>>(
        x, Wqt, bq, Wkt, bk, qb, kb, xh, N);

    // degree histogram (by src)
    hist_kernel<<<E / 256, 256, 0, stream>>>(ei, deg);

    // CSR offsets: two-level scan (+ bucket cursors)
    const int nb = (N + 1023) / 1024;
    scan1<<<nb, 1024, 0, stream>>>(deg, off, part, N);
    scan2<<<1, 64, 0, stream>>>(part, off + N, nb);
    scan3<<<nb, 1024, 0, stream>>>(off, bcur, part, N);

    // two-phase binned CSR fill
    bin_edges<<<(E + CHUNK - 1) / CHUNK, 256, 0, stream>>>(ei, bcur, tmp);
    place_edges<<<NBUCK, 256, 0, stream>>>(tmp, off, epack, N);

    // CSR-ordered scores -> exp (bf16) -> segment sums
    score_csr<<<(N * 64 + 255) / 256, 256, 0, stream>>>(
        qb, kb, off, epack, evals16, nsum, N);

    // attention mean, packed in place
    finalize_kernel<<<E / 256, 256, 0, stream>>>(evals16, nsum, epack);

    // 4 Euler steps, fp16 state chain: xh -> z1 -> z2 -> z3 -> out(fp32)
    const int sg = (N * 64 + 255) / 256;
    spmv_h<0><<<sg, 256, 0, stream>>>(xh, z1, nullptr, off, epack, N);
    spmv_h<0><<<sg, 256, 0, stream>>>(z1, z2, nullptr, off, epack, N);
    spmv_h<0><<<sg, 256, 0, stream>>>(z2, z3, nullptr, off, epack, N);
    spmv_h<1><<<sg, 256, 0, stream>>>(z3, nullptr, out, off, epack, N);
}

// Round 13
// 286.501 us; speedup vs baseline: 1.2304x; 1.0264x over previous
//
#include <hip/hip_runtime.h>
#include <hip/hip_fp16.h>

#define NODES 50000
#define EDGES 800000
#define HID   128
#define HEADS 4
// DK = 32, scale = 1/sqrt(32)
#define SCORE_SCALE 0.17677669529663687f

#define NBUCK ((NODES + 255) >> 8)   // 196 buckets of 256 src nodes
#define CHUNK 4096

typedef unsigned int       u32;
typedef unsigned short     u16;
typedef unsigned long long u64;

typedef __attribute__((ext_vector_type(8))) short bf16x8;
typedef __attribute__((ext_vector_type(4))) float f32x4;

// round-to-nearest-even f32 -> bf16
__device__ __forceinline__ u16 f2bf(float f) {
    u32 u = __builtin_bit_cast(u32, f);
    return (u16)((u + 0x7FFFu + ((u >> 16) & 1u)) >> 16);
}
__device__ __forceinline__ float bflo(u32 u) { return __builtin_bit_cast(float, u << 16); }
__device__ __forceinline__ float bfhi(u32 u) { return __builtin_bit_cast(float, u & 0xFFFF0000u); }
__device__ __forceinline__ float bdot2(u32 a, u32 b) {
    return bflo(a) * bflo(b) + bfhi(a) * bfhi(b);
}
// fp16 pair <-> f32 pair
__device__ __forceinline__ float2 h2f2(u32 u) {
    __half2 h = __builtin_bit_cast(__half2, u);
    return __half22float2(h);
}
__device__ __forceinline__ u32 f2h2(float a, float b) {
    __half2 h = __floats2half2_rn(a, b);
    return __builtin_bit_cast(u32, h);
}

// ---------------------------------------------------------------------------
// W prep: Wt[n][k] = bf16(W[k][n]), both 128x128. 2 matrices.
// ---------------------------------------------------------------------------
__global__ __launch_bounds__(256) void wprep(
    const float* __restrict__ Wq, const float* __restrict__ Wk,
    u16* __restrict__ Wqt, u16* __restrict__ Wkt)
{
    int e   = blockIdx.x * 256 + threadIdx.x;
    int mat = e >> 14;
    int idx = e & 16383;
    int k  = idx >> 7;
    int nn = idx & 127;
    const float* W = mat ? Wk : Wq;
    u16*        Wt = mat ? Wkt : Wqt;
    Wt[nn * 128 + k] = f2bf(W[idx]);
}

// ---------------------------------------------------------------------------
// MFMA Q/K projection. Wave = one 16-row tile, both matrices.
// Also emits row-major fp16 copy of x (xh) for the Euler gathers.
// ---------------------------------------------------------------------------
__global__ __launch_bounds__(256) void gemm_qk_mfma(
    const float* __restrict__ x,
    const u16* __restrict__ Wqt, const float* __restrict__ bq,
    const u16* __restrict__ Wkt, const float* __restrict__ bk,
    u16* __restrict__ qb, u16* __restrict__ kb, u16* __restrict__ xh, int n)
{
    const int l  = threadIdx.x & 63;
    const int w  = threadIdx.x >> 6;
    const int lr = l & 15;
    const int kg = l >> 4;

    const int arow   = blockIdx.x * 64 + w * 16 + lr;
    const bool av    = (arow < n);
    const int  arowc = av ? arow : (n - 1);

    bf16x8 afrag[4];
    #pragma unroll
    for (int ks = 0; ks < 4; ++ks) {
        const float* px = x + (size_t)arowc * HID + ks * 32 + kg * 8;
        float4 p0 = *(const float4*)px;
        float4 p1 = *(const float4*)(px + 4);
        uint4 pk;
        pk.x = (u32)f2bf(p0.x) | ((u32)f2bf(p0.y) << 16);
        pk.y = (u32)f2bf(p0.z) | ((u32)f2bf(p0.w) << 16);
        pk.z = (u32)f2bf(p1.x) | ((u32)f2bf(p1.y) << 16);
        pk.w = (u32)f2bf(p1.z) | ((u32)f2bf(p1.w) << 16);
        afrag[ks] = __builtin_bit_cast(bf16x8, pk);
        if (av) {
            uint4 ph;
            ph.x = f2h2(p0.x, p0.y);
            ph.y = f2h2(p0.z, p0.w);
            ph.z = f2h2(p1.x, p1.y);
            ph.w = f2h2(p1.z, p1.w);
            *(uint4*)(xh + (size_t)arow * HID + ks * 32 + kg * 8) = ph;
        }
    }

    #pragma unroll
    for (int mat = 0; mat < 2; ++mat) {
        const u16*   Wt   = mat ? Wkt : Wqt;
        const float* bias = mat ? bk : bq;
        u16*         outp = mat ? kb : qb;

        #pragma unroll
        for (int cb = 0; cb < 8; ++cb) {
            float bc = bias[cb * 16 + lr];
            f32x4 acc = {bc, bc, bc, bc};
            #pragma unroll
            for (int ks = 0; ks < 4; ++ks) {
                bf16x8 bfrag = __builtin_bit_cast(bf16x8,
                    *(const uint4*)(Wt + (size_t)(cb * 16 + lr) * 128 + ks * 32 + kg * 8));
                acc = __builtin_amdgcn_mfma_f32_16x16x32_bf16(afrag[ks], bfrag, acc, 0, 0, 0);
            }
            #pragma unroll
            for (int reg = 0; reg < 4; ++reg) {
                int gr = blockIdx.x * 64 + w * 16 + kg * 4 + reg;
                if (gr < n) outp[(size_t)gr * HID + cb * 16 + lr] = f2bf(acc[reg]);
            }
        }
    }
}

// ---------------------------------------------------------------------------
// out-degree histogram over src
// ---------------------------------------------------------------------------
__global__ __launch_bounds__(256) void hist_kernel(
    const int* __restrict__ ei, int* __restrict__ deg)
{
    int i = blockIdx.x * 256 + threadIdx.x;
    if (i < EDGES) atomicAdd(&deg[ei[i]], 1);
}

// ---------------------------------------------------------------------------
// two-level exclusive scan of deg -> off; also emits bucket cursors
// ---------------------------------------------------------------------------
__global__ __launch_bounds__(1024) void scan1(
    const int* __restrict__ deg, int* __restrict__ off,
    int* __restrict__ part, int n)
{
    __shared__ int sd[1024];
    int t = threadIdx.x, i = blockIdx.x * 1024 + t;
    int v = (i < n) ? deg[i] : 0;
    sd[t] = v;
    __syncthreads();
    #pragma unroll
    for (int o = 1; o < 1024; o <<= 1) {
        int a = (t >= o) ? sd[t - o] : 0;
        __syncthreads();
        sd[t] += a;
        __syncthreads();
    }
    if (i < n) off[i] = sd[t] - v;
    if (t == 1023) part[blockIdx.x] = sd[1023];
}

__global__ __launch_bounds__(64) void scan2(int* __restrict__ part,
                                            int* __restrict__ off_n, int nb)
{
    int t = threadIdx.x;
    int v = (t < nb) ? part[t] : 0;
    int orig = v;
    #pragma unroll
    for (int o = 1; o < 64; o <<= 1) {
        int a = __shfl_up(v, o);
        if (t >= o) v += a;
    }
    if (t < nb) part[t] = v - orig;
    if (t == 63) *off_n = v;
}

__global__ __launch_bounds__(1024) void scan3(
    int* __restrict__ off, int* __restrict__ bcur,
    const int* __restrict__ part, int n)
{
    int i = blockIdx.x * 1024 + threadIdx.x;
    if (i < n) {
        int o = off[i] + part[blockIdx.x];
        off[i] = o;
        if ((i & 255) == 0) bcur[i >> 8] = o;   // bucket base cursor
    }
}

// ---------------------------------------------------------------------------
// Phase 1: bin edges by bucket (src>>8) into tmp, bucket-contiguous.
// ---------------------------------------------------------------------------
__global__ __launch_bounds__(256) void bin_edges(
    const int* __restrict__ ei, int* __restrict__ bcur, u32* __restrict__ tmp)
{
    __shared__ u32 buf[CHUNK];
    __shared__ int hist[NBUCK];
    __shared__ int lcur[NBUCK];

    const int t  = threadIdx.x;
    const int e0 = blockIdx.x * CHUNK;
    const int e1 = (e0 + CHUNK < EDGES) ? e0 + CHUNK : EDGES;
    const int cnt = e1 - e0;

    for (int b = t; b < NBUCK; b += 256) hist[b] = 0;
    __syncthreads();

    for (int i = t; i < cnt; i += 256) {
        int src = ei[e0 + i];
        int dst = ei[EDGES + e0 + i];
        buf[i] = (u32)dst | ((u32)(src & 255) << 16) | ((u32)(src >> 8) << 24);
        atomicAdd(&hist[src >> 8], 1);
    }
    __syncthreads();

    for (int b = t; b < NBUCK; b += 256) {
        int h = hist[b];
        lcur[b] = h ? atomicAdd(&bcur[b], h) : 0;
    }
    __syncthreads();

    for (int i = t; i < cnt; i += 256) {
        u32 pk  = buf[i];
        int b   = pk >> 24;
        int pos = atomicAdd(&lcur[b], 1);
        tmp[pos] = pk & 0x00FFFFFFu;          // srcLocal<<16 | dst
    }
}

// ---------------------------------------------------------------------------
// Phase 2: exact CSR placement within each bucket (LDS cursors, local window)
// ---------------------------------------------------------------------------
__global__ __launch_bounds__(256) void place_edges(
    const u32* __restrict__ tmp, const int* __restrict__ off,
    u32* __restrict__ epack, int n)
{
    __shared__ int lcur[256];
    const int t     = threadIdx.x;
    const int nbase = blockIdx.x << 8;
    const int nend  = (nbase + 256 < n) ? nbase + 256 : n;

    if (nbase + t < nend) lcur[t] = off[nbase + t];
    __syncthreads();

    const int s0 = off[nbase];
    const int s1 = off[nend];
    for (int i = s0 + t; i < s1; i += 256) {
        u32 pk    = tmp[i];
        int local = pk >> 16;
        int pos   = atomicAdd(&lcur[local], 1);
        epack[pos] = pk & 0xFFFFu;            // dst only (att packed later)
    }
}

// ---------------------------------------------------------------------------
// CSR-ordered scores: wave per src node, 4 groups x 16 lanes, 4-deep gather
// pipelining per group (r9-proven; r12's 8-deep raised VGPR->56, occ 64->34%,
// dur +4us -- reverted). q[src] loaded once. e-values stored packed bf16.
// ---------------------------------------------------------------------------
__global__ __launch_bounds__(256) void score_csr(
    const u16* __restrict__ qb, const u16* __restrict__ kb,
    const int* __restrict__ off, const u32* __restrict__ ccol,
    u16* __restrict__ evals16, float* __restrict__ nsum, int n)
{
    const int wv   = (blockIdx.x * 256 + threadIdx.x) >> 6;   // src node
    const int lane = threadIdx.x & 63;
    const int l16  = lane & 15;
    const int grp  = lane >> 4;
    if (wv >= n) return;

    const int beg = off[wv];
    const int end = off[wv + 1];

    uint4 qv = *(const uint4*)(qb + (size_t)wv * HID + l16 * 8);

    for (int j = beg; j < end; j += 16) {
        u32 d[4]; uint4 kv[4];
        #pragma unroll
        for (int u = 0; u < 4; ++u) {
            int e  = j + grp + u * 4;
            int ec = (e < end) ? e : (end - 1);
            d[u] = ccol[ec];
        }
        #pragma unroll
        for (int u = 0; u < 4; ++u)
            kv[u] = *(const uint4*)(kb + (size_t)d[u] * HID + l16 * 8);
        #pragma unroll
        for (int u = 0; u < 4; ++u) {
            int e = j + grp + u * 4;
            float p = bdot2(qv.x, kv[u].x) + bdot2(qv.y, kv[u].y) +
                      bdot2(qv.z, kv[u].z) + bdot2(qv.w, kv[u].w);
            p += __shfl_xor(p, 1);
            p += __shfl_xor(p, 2);
            if (e < end && (l16 & 3) == 0) {
                int head = l16 >> 2;
                float ev = __expf(p * SCORE_SCALE);
                evals16[(size_t)e * HEADS + head] = f2bf(ev);
                atomicAdd(&nsum[(size_t)d[u] * HEADS + head], ev);
            }
        }
    }
}

// ---------------------------------------------------------------------------
// head-mean attention; packs epack[pos] = dst | bf16(att)<<16 IN PLACE.
// ---------------------------------------------------------------------------
__global__ __launch_bounds__(256) void finalize_kernel(
    const u16* __restrict__ evals16, const float* __restrict__ nsum,
    u32* __restrict__ epack)
{
    int pos = blockIdx.x * 256 + threadIdx.x;
    if (pos >= EDGES) return;
    u32 dst = epack[pos];
    u64 ev8 = *(const u64*)(evals16 + (size_t)pos * HEADS);
    u32 lo = (u32)ev8, hi = (u32)(ev8 >> 32);
    float4 sv = *(const float4*)(nsum + (size_t)dst * HEADS);
    float am = 0.25f * (bflo(lo) / (sv.x + 1e-16f) + bfhi(lo) / (sv.y + 1e-16f) +
                        bflo(hi) / (sv.z + 1e-16f) + bfhi(hi) / (sv.w + 1e-16f));
    epack[pos] = dst | ((u32)f2bf(am) << 16);
}

// ---------------------------------------------------------------------------
// SCALARIZED Euler step. Node w is wave-uniform -> beg/end/epack values are
// wave-uniform: readfirstlane forces them into SGPRs, so (a) epack loads are
// scalar loads (no per-lane load, no shfl broadcast), (b) the &0xFFFF and
// row-offset math run on the SCALAR pipe, (c) gathers are SGPR-base +
// loop-invariant VGPR lane offset -> ZERO per-edge vector address math.
// Per-edge VALU drops ~11 -> ~4 instrs (r12 diagnosis: passes are VALU/issue
// bound -- VALUBusy 40-48%, invariant to bytes moved r9 vs r11).
// NOTE (r7): keep wave count high; (r12): keep VGPR low for occupancy.
// ---------------------------------------------------------------------------
template<int FINAL>
__global__ __launch_bounds__(256) void spmv_h(
    const u16* __restrict__ inh, u16* __restrict__ outh,
    float* __restrict__ outf,
    const int* __restrict__ off, const u32* __restrict__ epack, int n)
{
    const int w    = (blockIdx.x * 256 + threadIdx.x) >> 6;
    const int lane = threadIdx.x & 63;
    if (w >= n) return;

    const int beg = __builtin_amdgcn_readfirstlane(off[w]);
    const int end = __builtin_amdgcn_readfirstlane(off[w + 1]);

    const u32* inw = (const u32*)inh;          // 64 u32 per 128-dim row

    float ax = 0.f, ay = 0.f;
    int j = beg;
    for (; j + 8 <= end; j += 8) {
        u32 e[8], s[8];
        #pragma unroll
        for (int u = 0; u < 8; ++u) e[u] = epack[j + u];        // uniform -> SGPR
        #pragma unroll
        for (int u = 0; u < 8; ++u)
            s[u] = inw[(size_t)(e[u] & 0xFFFFu) * 64 + lane];   // SGPR base + lane
        #pragma unroll
        for (int u = 0; u < 8; ++u) {
            float vv = bfhi(e[u]);                              // scalar AND
            float2 sv = h2f2(s[u]);
            ax += vv * sv.x;
            ay += vv * sv.y;
        }
    }
    for (; j + 4 <= end; j += 4) {
        u32 e[4], s[4];
        #pragma unroll
        for (int u = 0; u < 4; ++u) e[u] = epack[j + u];
        #pragma unroll
        for (int u = 0; u < 4; ++u)
            s[u] = inw[(size_t)(e[u] & 0xFFFFu) * 64 + lane];
        #pragma unroll
        for (int u = 0; u < 4; ++u) {
            float vv = bfhi(e[u]);
            float2 sv = h2f2(s[u]);
            ax += vv * sv.x;
            ay += vv * sv.y;
        }
    }
    for (; j < end; ++j) {
        u32 e = epack[j];
        u32 s = inw[(size_t)(e & 0xFFFFu) * 64 + lane];
        float vv = bfhi(e);
        float2 sv = h2f2(s);
        ax += vv * sv.x;
        ay += vv * sv.y;
    }

    u32 zi = inw[(size_t)w * 64 + lane];
    float2 xi = h2f2(zi);
    const float ox = 0.75f * xi.x + 0.25f * ax;
    const float oy = 0.75f * xi.y + 0.25f * ay;
    if (FINAL) {
        float2 o; o.x = ox; o.y = oy;
        *(float2*)(outf + (size_t)w * HID + lane * 2) = o;
    } else {
        *(u32*)(outh + (size_t)w * HID + lane * 2) = f2h2(ox, oy);
    }
}

// ---------------------------------------------------------------------------
extern "C" void kernel_launch(void* const* d_in, const int* in_sizes, int n_in,
                              void* d_out, int out_size, void* d_ws, size_t ws_size,
                              hipStream_t stream)
{
    (void)in_sizes; (void)n_in; (void)out_size; (void)ws_size;

    const float* x  = (const float*)d_in[0];
    const float* Wq = (const float*)d_in[1];
    const float* bq = (const float*)d_in[2];
    const float* Wk = (const float*)d_in[3];
    const float* bk = (const float*)d_in[4];
    const int*   ei = (const int*)d_in[5];
    float* out = (float*)d_out;

    const int N = NODES, E = EDGES;
    const size_t ROWB_B = (size_t)N * HID * 2;   // 12.8 MB 16-bit state

    char* ws = (char*)d_ws;
    // region A (25.6 MB): qb|kb -- dead after score_csr -- reused as z1|z2
    u16*   qb    = (u16*)(ws);
    u16*   kb    = (u16*)(ws + ROWB_B);
    u16*   z1    = (u16*)(ws);
    u16*   z2    = (u16*)(ws + ROWB_B);
    ws += 2 * ROWB_B;
    // xh: fp16 copy of x, live through euler step 1
    u16*   xh    = (u16*)ws;  ws += ROWB_B;
    // evals16 (6.4 MB used) -- dead after finalize -- region reused as z3
    u16*   evals16 = (u16*)ws;
    u16*   z3    = (u16*)ws;  ws += (size_t)E * HEADS * 4;   // 12.8 MB region
    float* nsum  = (float*)ws; ws += (size_t)N * HEADS * 4;
    int*   deg   = (int*)ws;   ws += (size_t)N * 4;
    int*   off   = (int*)ws;   ws += ((size_t)(N + 1) * 4 + 255) & ~255ull;
    int*   bcur  = (int*)ws;   ws += ((size_t)NBUCK * 4 + 255) & ~255ull;
    int*   part  = (int*)ws;   ws += 256;
    u32*   epack = (u32*)ws;   ws += (size_t)E * 4;   // dst-only CSR, then packed
    u32*   tmp   = (u32*)ws;   ws += (size_t)E * 4;   // bucket-grouped edges
    u16*   Wqt   = (u16*)ws;   ws += (size_t)128 * 128 * 2;
    u16*   Wkt   = (u16*)ws;   ws += (size_t)128 * 128 * 2;

    // zero nsum + deg (contiguous)
    hipMemsetAsync(nsum, 0, (size_t)N * HEADS * 4 + (size_t)N * 4, stream);

    // W -> bf16 transposed
    wprep<<<128, 256, 0, stream>>>(Wq, Wk, Wqt, Wkt);

    // Q/K projections via MFMA (bf16 out) + fp16 copy of x
    gemm_qk_mfma<<<(N + 63) / 64, 256, 0, stream>>>(
        x, Wqt, bq, Wkt, bk, qb, kb, xh, N);

    // degree histogram (by src)
    hist_kernel<<<E / 256, 256, 0, stream>>>(ei, deg);

    // CSR offsets: two-level scan (+ bucket cursors)
    const int nb = (N + 1023) / 1024;
    scan1<<<nb, 1024, 0, stream>>>(deg, off, part, N);
    scan2<<<1, 64, 0, stream>>>(part, off + N, nb);
    scan3<<<nb, 1024, 0, stream>>>(off, bcur, part, N);

    // two-phase binned CSR fill
    bin_edges<<<(E + CHUNK - 1) / CHUNK, 256, 0, stream>>>(ei, bcur, tmp);
    place_edges<<<NBUCK, 256, 0, stream>>>(tmp, off, epack, N);

    // CSR-ordered scores -> exp (bf16) -> segment sums
    score_csr<<<(N * 64 + 255) / 256, 256, 0, stream>>>(
        qb, kb, off, epack, evals16, nsum, N);

    // attention mean, packed in place
    finalize_kernel<<<E / 256, 256, 0, stream>>>(evals16, nsum, epack);

    // 4 Euler steps, fp16 state chain: xh -> z1 -> z2 -> z3 -> out(fp32)
    const int sg = (N * 64 + 255) / 256;
    spmv_h<0><<<sg, 256, 0, stream>>>(xh, z1, nullptr, off, epack, N);
    spmv_h<0><<<sg, 256, 0, stream>>>(z1, z2, nullptr, off, epack, N);
    spmv_h<0><<<sg, 256, 0, stream>>>(z2, z3, nullptr, off, epack, N);
    spmv_h<1><<<sg, 256, 0, stream>>>(z3, nullptr, out, off, epack, N);
}

// Round 14
// 265.489 us; speedup vs baseline: 1.3278x; 1.0791x over previous
//
#include <hip/hip_runtime.h>
#include <hip/hip_fp16.h>

#define NODES 50000
#define EDGES 800000
#define HID   128
#define HEADS 4
// DK = 32, scale = 1/sqrt(32)
#define SCORE_SCALE 0.17677669529663687f

#define NBUCK ((NODES + 255) >> 8)   // 196 buckets of 256 src nodes
#define CHUNK 4096

typedef unsigned int       u32;
typedef unsigned short     u16;
typedef unsigned char      u8;
typedef unsigned long long u64;

typedef __attribute__((ext_vector_type(8))) short bf16x8;
typedef __attribute__((ext_vector_type(4))) float f32x4;
typedef __attribute__((ext_vector_type(2))) float f32x2;

// round-to-nearest-even f32 -> bf16
__device__ __forceinline__ u16 f2bf(float f) {
    u32 u = __builtin_bit_cast(u32, f);
    return (u16)((u + 0x7FFFu + ((u >> 16) & 1u)) >> 16);
}
__device__ __forceinline__ float bflo(u32 u) { return __builtin_bit_cast(float, u << 16); }
__device__ __forceinline__ float bfhi(u32 u) { return __builtin_bit_cast(float, u & 0xFFFF0000u); }
// fp16 pair <-> f32 pair
__device__ __forceinline__ float2 h2f2(u32 u) {
    __half2 h = __builtin_bit_cast(__half2, u);
    return __half22float2(h);
}
__device__ __forceinline__ u32 f2h2(float a, float b) {
    __half2 h = __floats2half2_rn(a, b);
    return __builtin_bit_cast(u32, h);
}

// ---------------------------------------------------------------------------
// W prep: Wt[n][k] = bf16(W[k][n]), both 128x128. 2 matrices.
// ---------------------------------------------------------------------------
__global__ __launch_bounds__(256) void wprep(
    const float* __restrict__ Wq, const float* __restrict__ Wk,
    u16* __restrict__ Wqt, u16* __restrict__ Wkt)
{
    int e   = blockIdx.x * 256 + threadIdx.x;
    int mat = e >> 14;
    int idx = e & 16383;
    int k  = idx >> 7;
    int nn = idx & 127;
    const float* W = mat ? Wk : Wq;
    u16*        Wt = mat ? Wkt : Wqt;
    Wt[nn * 128 + k] = f2bf(W[idx]);
}

// ---------------------------------------------------------------------------
// MFMA Q/K projection. Wave = one 16-row tile, both matrices.
// Outputs: qb (bf16, sequential reads in score), k8 (fp8, gathered in score),
// xh (fp16 master), x8 (fp8 gather copy) -- gathered rows are fp8 = 128B.
// ---------------------------------------------------------------------------
__global__ __launch_bounds__(256) void gemm_qk_mfma(
    const float* __restrict__ x,
    const u16* __restrict__ Wqt, const float* __restrict__ bq,
    const u16* __restrict__ Wkt, const float* __restrict__ bk,
    u16* __restrict__ qb, u8* __restrict__ k8,
    u16* __restrict__ xh, u8* __restrict__ x8, int n)
{
    const int l  = threadIdx.x & 63;
    const int w  = threadIdx.x >> 6;
    const int lr = l & 15;
    const int kg = l >> 4;

    const int arow   = blockIdx.x * 64 + w * 16 + lr;
    const bool av    = (arow < n);
    const int  arowc = av ? arow : (n - 1);

    bf16x8 afrag[4];
    #pragma unroll
    for (int ks = 0; ks < 4; ++ks) {
        const float* px = x + (size_t)arowc * HID + ks * 32 + kg * 8;
        float4 p0 = *(const float4*)px;
        float4 p1 = *(const float4*)(px + 4);
        uint4 pk;
        pk.x = (u32)f2bf(p0.x) | ((u32)f2bf(p0.y) << 16);
        pk.y = (u32)f2bf(p0.z) | ((u32)f2bf(p0.w) << 16);
        pk.z = (u32)f2bf(p1.x) | ((u32)f2bf(p1.y) << 16);
        pk.w = (u32)f2bf(p1.z) | ((u32)f2bf(p1.w) << 16);
        afrag[ks] = __builtin_bit_cast(bf16x8, pk);
        if (av) {
            uint4 ph;
            ph.x = f2h2(p0.x, p0.y);
            ph.y = f2h2(p0.z, p0.w);
            ph.z = f2h2(p1.x, p1.y);
            ph.w = f2h2(p1.z, p1.w);
            *(uint4*)(xh + (size_t)arow * HID + ks * 32 + kg * 8) = ph;
            // fp8 copy (8 dims -> 8 bytes)
            u32 w0 = __builtin_amdgcn_cvt_pk_fp8_f32(p0.x, p0.y, 0u, false);
            w0     = __builtin_amdgcn_cvt_pk_fp8_f32(p0.z, p0.w, w0, true);
            u32 w1 = __builtin_amdgcn_cvt_pk_fp8_f32(p1.x, p1.y, 0u, false);
            w1     = __builtin_amdgcn_cvt_pk_fp8_f32(p1.z, p1.w, w1, true);
            uint2 pv; pv.x = w0; pv.y = w1;
            *(uint2*)(x8 + (size_t)arow * HID + ks * 32 + kg * 8) = pv;
        }
    }

    #pragma unroll
    for (int mat = 0; mat < 2; ++mat) {
        const u16*   Wt   = mat ? Wkt : Wqt;
        const float* bias = mat ? bk : bq;

        #pragma unroll
        for (int cb = 0; cb < 8; ++cb) {
            float bc = bias[cb * 16 + lr];
            f32x4 acc = {bc, bc, bc, bc};
            #pragma unroll
            for (int ks = 0; ks < 4; ++ks) {
                bf16x8 bfrag = __builtin_bit_cast(bf16x8,
                    *(const uint4*)(Wt + (size_t)(cb * 16 + lr) * 128 + ks * 32 + kg * 8));
                acc = __builtin_amdgcn_mfma_f32_16x16x32_bf16(afrag[ks], bfrag, acc, 0, 0, 0);
            }
            #pragma unroll
            for (int reg = 0; reg < 4; ++reg) {
                int gr = blockIdx.x * 64 + w * 16 + kg * 4 + reg;
                if (gr < n) {
                    if (mat == 0) {
                        qb[(size_t)gr * HID + cb * 16 + lr] = f2bf(acc[reg]);
                    } else {
                        u32 p8 = __builtin_amdgcn_cvt_pk_fp8_f32(acc[reg], 0.f, 0u, false);
                        k8[(size_t)gr * HID + cb * 16 + lr] = (u8)(p8 & 0xFFu);
                    }
                }
            }
        }
    }
}

// ---------------------------------------------------------------------------
// out-degree histogram over src
// ---------------------------------------------------------------------------
__global__ __launch_bounds__(256) void hist_kernel(
    const int* __restrict__ ei, int* __restrict__ deg)
{
    int i = blockIdx.x * 256 + threadIdx.x;
    if (i < EDGES) atomicAdd(&deg[ei[i]], 1);
}

// ---------------------------------------------------------------------------
// two-level exclusive scan of deg -> off; also emits bucket cursors
// ---------------------------------------------------------------------------
__global__ __launch_bounds__(1024) void scan1(
    const int* __restrict__ deg, int* __restrict__ off,
    int* __restrict__ part, int n)
{
    __shared__ int sd[1024];
    int t = threadIdx.x, i = blockIdx.x * 1024 + t;
    int v = (i < n) ? deg[i] : 0;
    sd[t] = v;
    __syncthreads();
    #pragma unroll
    for (int o = 1; o < 1024; o <<= 1) {
        int a = (t >= o) ? sd[t - o] : 0;
        __syncthreads();
        sd[t] += a;
        __syncthreads();
    }
    if (i < n) off[i] = sd[t] - v;
    if (t == 1023) part[blockIdx.x] = sd[1023];
}

__global__ __launch_bounds__(64) void scan2(int* __restrict__ part,
                                            int* __restrict__ off_n, int nb)
{
    int t = threadIdx.x;
    int v = (t < nb) ? part[t] : 0;
    int orig = v;
    #pragma unroll
    for (int o = 1; o < 64; o <<= 1) {
        int a = __shfl_up(v, o);
        if (t >= o) v += a;
    }
    if (t < nb) part[t] = v - orig;
    if (t == 63) *off_n = v;
}

__global__ __launch_bounds__(1024) void scan3(
    int* __restrict__ off, int* __restrict__ bcur,
    const int* __restrict__ part, int n)
{
    int i = blockIdx.x * 1024 + threadIdx.x;
    if (i < n) {
        int o = off[i] + part[blockIdx.x];
        off[i] = o;
        if ((i & 255) == 0) bcur[i >> 8] = o;   // bucket base cursor
    }
}

// ---------------------------------------------------------------------------
// Phase 1: bin edges by bucket (src>>8) into tmp, bucket-contiguous.
// ---------------------------------------------------------------------------
__global__ __launch_bounds__(256) void bin_edges(
    const int* __restrict__ ei, int* __restrict__ bcur, u32* __restrict__ tmp)
{
    __shared__ u32 buf[CHUNK];
    __shared__ int hist[NBUCK];
    __shared__ int lcur[NBUCK];

    const int t  = threadIdx.x;
    const int e0 = blockIdx.x * CHUNK;
    const int e1 = (e0 + CHUNK < EDGES) ? e0 + CHUNK : EDGES;
    const int cnt = e1 - e0;

    for (int b = t; b < NBUCK; b += 256) hist[b] = 0;
    __syncthreads();

    for (int i = t; i < cnt; i += 256) {
        int src = ei[e0 + i];
        int dst = ei[EDGES + e0 + i];
        buf[i] = (u32)dst | ((u32)(src & 255) << 16) | ((u32)(src >> 8) << 24);
        atomicAdd(&hist[src >> 8], 1);
    }
    __syncthreads();

    for (int b = t; b < NBUCK; b += 256) {
        int h = hist[b];
        lcur[b] = h ? atomicAdd(&bcur[b], h) : 0;
    }
    __syncthreads();

    for (int i = t; i < cnt; i += 256) {
        u32 pk  = buf[i];
        int b   = pk >> 24;
        int pos = atomicAdd(&lcur[b], 1);
        tmp[pos] = pk & 0x00FFFFFFu;          // srcLocal<<16 | dst
    }
}

// ---------------------------------------------------------------------------
// Phase 2: exact CSR placement within each bucket (LDS cursors, local window)
// ---------------------------------------------------------------------------
__global__ __launch_bounds__(256) void place_edges(
    const u32* __restrict__ tmp, const int* __restrict__ off,
    u32* __restrict__ epack, int n)
{
    __shared__ int lcur[256];
    const int t     = threadIdx.x;
    const int nbase = blockIdx.x << 8;
    const int nend  = (nbase + 256 < n) ? nbase + 256 : n;

    if (nbase + t < nend) lcur[t] = off[nbase + t];
    __syncthreads();

    const int s0 = off[nbase];
    const int s1 = off[nend];
    for (int i = s0 + t; i < s1; i += 256) {
        u32 pk    = tmp[i];
        int local = pk >> 16;
        int pos   = atomicAdd(&lcur[local], 1);
        epack[pos] = pk & 0xFFFFu;            // dst only (att packed later)
    }
}

// ---------------------------------------------------------------------------
// CSR-ordered scores: wave per src node, 4 groups x 16 lanes, 4-deep gather
// pipelining. q[src] bf16 loaded once; k gathered as fp8 rows (128B, half of
// bf16) -- r13 model: pass time ~ logical gathered bytes (TCP-bound).
// HW decode via v_cvt_pk_f32_fp8. e-values stored packed bf16.
// ---------------------------------------------------------------------------
__global__ __launch_bounds__(256) void score_csr(
    const u16* __restrict__ qb, const u8* __restrict__ k8,
    const int* __restrict__ off, const u32* __restrict__ ccol,
    u16* __restrict__ evals16, float* __restrict__ nsum, int n)
{
    const int wv   = (blockIdx.x * 256 + threadIdx.x) >> 6;   // src node
    const int lane = threadIdx.x & 63;
    const int l16  = lane & 15;
    const int grp  = lane >> 4;
    if (wv >= n) return;

    const int beg = off[wv];
    const int end = off[wv + 1];

    uint4 qv = *(const uint4*)(qb + (size_t)wv * HID + l16 * 8);

    for (int j = beg; j < end; j += 16) {
        u32 d[4]; u64 kv[4];
        #pragma unroll
        for (int u = 0; u < 4; ++u) {
            int e  = j + grp + u * 4;
            int ec = (e < end) ? e : (end - 1);
            d[u] = ccol[ec];
        }
        #pragma unroll
        for (int u = 0; u < 4; ++u)
            kv[u] = *(const u64*)(k8 + (size_t)d[u] * HID + l16 * 8);
        #pragma unroll
        for (int u = 0; u < 4; ++u) {
            int e = j + grp + u * 4;
            u32 klo = (u32)kv[u], khi = (u32)(kv[u] >> 32);
            f32x2 a = __builtin_amdgcn_cvt_pk_f32_fp8(klo, false);
            f32x2 b = __builtin_amdgcn_cvt_pk_f32_fp8(klo, true);
            f32x2 c = __builtin_amdgcn_cvt_pk_f32_fp8(khi, false);
            f32x2 dd= __builtin_amdgcn_cvt_pk_f32_fp8(khi, true);
            float p = bflo(qv.x) * a.x + bfhi(qv.x) * a.y
                    + bflo(qv.y) * b.x + bfhi(qv.y) * b.y
                    + bflo(qv.z) * c.x + bfhi(qv.z) * c.y
                    + bflo(qv.w) * dd.x + bfhi(qv.w) * dd.y;
            p += __shfl_xor(p, 1);
            p += __shfl_xor(p, 2);
            if (e < end && (l16 & 3) == 0) {
                int head = l16 >> 2;
                float ev = __expf(p * SCORE_SCALE);
                evals16[(size_t)e * HEADS + head] = f2bf(ev);
                atomicAdd(&nsum[(size_t)d[u] * HEADS + head], ev);
            }
        }
    }
}

// ---------------------------------------------------------------------------
// head-mean attention; packs epack[pos] = dst | bf16(att)<<16 IN PLACE.
// ---------------------------------------------------------------------------
__global__ __launch_bounds__(256) void finalize_kernel(
    const u16* __restrict__ evals16, const float* __restrict__ nsum,
    u32* __restrict__ epack)
{
    int pos = blockIdx.x * 256 + threadIdx.x;
    if (pos >= EDGES) return;
    u32 dst = epack[pos];
    u64 ev8 = *(const u64*)(evals16 + (size_t)pos * HEADS);
    u32 lo = (u32)ev8, hi = (u32)(ev8 >> 32);
    float4 sv = *(const float4*)(nsum + (size_t)dst * HEADS);
    float am = 0.25f * (bflo(lo) / (sv.x + 1e-16f) + bfhi(lo) / (sv.y + 1e-16f) +
                        bflo(hi) / (sv.z + 1e-16f) + bfhi(hi) / (sv.w + 1e-16f));
    epack[pos] = dst | ((u32)f2bf(am) << 16);
}

// ---------------------------------------------------------------------------
// SCALARIZED Euler step with fp8 gathers. Master state fp16 (never quantized
// to fp8 -- only the gathered COPY is fp8, so quantization noise enters only
// through the 0.25*A*z term). Gathered row = 128B (half of fp16): r9/r11/r13
// established pass time ~ logical gathered bytes at ~4.4 TB/s (TCP floor).
// Node w wave-uniform -> epack loads scalar (r13). Decode: v_cvt_pk_f32_fp8.
// NOTE (r7): keep wave count high; (r12): keep VGPR low for occupancy.
// ---------------------------------------------------------------------------
template<int FINAL>
__global__ __launch_bounds__(256) void spmv_h8(
    const u16* __restrict__ inh, const u8* __restrict__ in8,
    u16* __restrict__ outh, u8* __restrict__ out8,
    float* __restrict__ outf,
    const int* __restrict__ off, const u32* __restrict__ epack, int n)
{
    const int w    = (blockIdx.x * 256 + threadIdx.x) >> 6;
    const int lane = threadIdx.x & 63;
    if (w >= n) return;

    const int beg = __builtin_amdgcn_readfirstlane(off[w]);
    const int end = __builtin_amdgcn_readfirstlane(off[w + 1]);

    const u16* in8w = (const u16*)in8;         // 64 fp8-pairs per 128-dim row

    float ax = 0.f, ay = 0.f;
    int j = beg;
    for (; j + 8 <= end; j += 8) {
        u32 e[8], s[8];
        #pragma unroll
        for (int u = 0; u < 8; ++u) e[u] = epack[j + u];          // uniform -> SGPR
        #pragma unroll
        for (int u = 0; u < 8; ++u)
            s[u] = in8w[(size_t)(e[u] & 0xFFFFu) * 64 + lane];    // 2B/lane gather
        #pragma unroll
        for (int u = 0; u < 8; ++u) {
            float vv = bfhi(e[u]);
            f32x2 sv = __builtin_amdgcn_cvt_pk_f32_fp8(s[u], false);
            ax += vv * sv.x;
            ay += vv * sv.y;
        }
    }
    for (; j + 4 <= end; j += 4) {
        u32 e[4], s[4];
        #pragma unroll
        for (int u = 0; u < 4; ++u) e[u] = epack[j + u];
        #pragma unroll
        for (int u = 0; u < 4; ++u)
            s[u] = in8w[(size_t)(e[u] & 0xFFFFu) * 64 + lane];
        #pragma unroll
        for (int u = 0; u < 4; ++u) {
            float vv = bfhi(e[u]);
            f32x2 sv = __builtin_amdgcn_cvt_pk_f32_fp8(s[u], false);
            ax += vv * sv.x;
            ay += vv * sv.y;
        }
    }
    for (; j < end; ++j) {
        u32 e = epack[j];
        u32 s = in8w[(size_t)(e & 0xFFFFu) * 64 + lane];
        float vv = bfhi(e);
        f32x2 sv = __builtin_amdgcn_cvt_pk_f32_fp8(s, false);
        ax += vv * sv.x;
        ay += vv * sv.y;
    }

    // own row from fp16 MASTER (full precision path)
    u32 zi = *(const u32*)(inh + (size_t)w * HID + lane * 2);
    float2 xi = h2f2(zi);
    const float ox = 0.75f * xi.x + 0.25f * ax;
    const float oy = 0.75f * xi.y + 0.25f * ay;
    if (FINAL) {
        float2 o; o.x = ox; o.y = oy;
        *(float2*)(outf + (size_t)w * HID + lane * 2) = o;
    } else {
        *(u32*)(outh + (size_t)w * HID + lane * 2) = f2h2(ox, oy);
        u32 p8 = __builtin_amdgcn_cvt_pk_fp8_f32(ox, oy, 0u, false);
        ((u16*)out8)[(size_t)w * 64 + lane] = (u16)(p8 & 0xFFFFu);
    }
}

// ---------------------------------------------------------------------------
extern "C" void kernel_launch(void* const* d_in, const int* in_sizes, int n_in,
                              void* d_out, int out_size, void* d_ws, size_t ws_size,
                              hipStream_t stream)
{
    (void)in_sizes; (void)n_in; (void)out_size; (void)ws_size;

    const float* x  = (const float*)d_in[0];
    const float* Wq = (const float*)d_in[1];
    const float* bq = (const float*)d_in[2];
    const float* Wk = (const float*)d_in[3];
    const float* bk = (const float*)d_in[4];
    const int*   ei = (const int*)d_in[5];
    float* out = (float*)d_out;

    const int N = NODES, E = EDGES;
    const size_t ROWB_H = (size_t)N * HID * 2;   // 12.8 MB fp16 state
    const size_t ROWB_8 = (size_t)N * HID;       //  6.4 MB fp8 state

    char* ws = (char*)d_ws;
    // qb (dead after score) overlaid with z2h; k8 (dead after score) with z28
    u16*   qb   = (u16*)ws;
    u16*   z2h  = (u16*)ws;  ws += ROWB_H;
    u8*    k8   = (u8*)ws;
    u8*    z28  = (u8*)ws;   ws += ROWB_8;
    // xh/x8 (dead after spmv step 1) overlaid with z3h/z38
    u16*   xh   = (u16*)ws;
    u16*   z3h  = (u16*)ws;  ws += ROWB_H;
    u8*    x8   = (u8*)ws;
    u8*    z38  = (u8*)ws;   ws += ROWB_8;
    // evals16 (dead after finalize) overlaid with z18
    u16*   evals16 = (u16*)ws;
    u8*    z18  = (u8*)ws;   ws += (size_t)E * HEADS * 2;   // 6.4 MB
    u16*   z1h  = (u16*)ws;  ws += ROWB_H;
    float* nsum = (float*)ws; ws += (size_t)N * HEADS * 4;
    int*   deg  = (int*)ws;   ws += (size_t)N * 4;
    int*   off  = (int*)ws;   ws += ((size_t)(N + 1) * 4 + 255) & ~255ull;
    int*   bcur = (int*)ws;   ws += ((size_t)NBUCK * 4 + 255) & ~255ull;
    int*   part = (int*)ws;   ws += 256;
    u32*   epack = (u32*)ws;  ws += (size_t)E * 4;   // dst-only CSR, then packed
    u32*   tmp   = (u32*)ws;  ws += (size_t)E * 4;   // bucket-grouped edges
    u16*   Wqt   = (u16*)ws;  ws += (size_t)128 * 128 * 2;
    u16*   Wkt   = (u16*)ws;  ws += (size_t)128 * 128 * 2;

    // zero nsum + deg (contiguous)
    hipMemsetAsync(nsum, 0, (size_t)N * HEADS * 4 + (size_t)N * 4, stream);

    // W -> bf16 transposed
    wprep<<<128, 256, 0, stream>>>(Wq, Wk, Wqt, Wkt);

    // Q/K projections via MFMA: qb bf16, k8 fp8, xh fp16, x8 fp8
    gemm_qk_mfma<<<(N + 63) / 64, 256, 0, stream>>>(
        x, Wqt, bq, Wkt, bk, qb, k8, xh, x8, N);

    // degree histogram (by src)
    hist_kernel<<<E / 256, 256, 0, stream>>>(ei, deg);

    // CSR offsets: two-level scan (+ bucket cursors)
    const int nb = (N + 1023) / 1024;
    scan1<<<nb, 1024, 0, stream>>>(deg, off, part, N);
    scan2<<<1, 64, 0, stream>>>(part, off + N, nb);
    scan3<<<nb, 1024, 0, stream>>>(off, bcur, part, N);

    // two-phase binned CSR fill
    bin_edges<<<(E + CHUNK - 1) / CHUNK, 256, 0, stream>>>(ei, bcur, tmp);
    place_edges<<<NBUCK, 256, 0, stream>>>(tmp, off, epack, N);

    // CSR-ordered scores (fp8 k gathers) -> exp (bf16) -> segment sums
    score_csr<<<(N * 64 + 255) / 256, 256, 0, stream>>>(
        qb, k8, off, epack, evals16, nsum, N);

    // attention mean, packed in place
    finalize_kernel<<<E / 256, 256, 0, stream>>>(evals16, nsum, epack);

    // 4 Euler steps: fp16 master chain + fp8 gather copies
    const int sg = (N * 64 + 255) / 256;
    spmv_h8<0><<<sg, 256, 0, stream>>>(xh,  x8,  z1h, z18, nullptr, off, epack, N);
    spmv_h8<0><<<sg, 256, 0, stream>>>(z1h, z18, z2h, z28, nullptr, off, epack, N);
    spmv_h8<0><<<sg, 256, 0, stream>>>(z2h, z28, z3h, z38, nullptr, off, epack, N);
    spmv_h8<1><<<sg, 256, 0, stream>>>(z3h, z38, nullptr, nullptr, out, off, epack, N);
}

// Round 15
// 262.903 us; speedup vs baseline: 1.3408x; 1.0098x over previous
//
#include <hip/hip_runtime.h>
#include <hip/hip_fp16.h>

#define NODES 50000
#define EDGES 800000
#define HID   128
#define HEADS 4
// DK = 32, scale = 1/sqrt(32)
#define SCORE_SCALE 0.17677669529663687f

#define NBUCK ((NODES + 255) >> 8)   // 196 buckets of 256 src nodes
#define CHUNK 4096

typedef unsigned int       u32;
typedef unsigned short     u16;
typedef unsigned char      u8;
typedef unsigned long long u64;

typedef __attribute__((ext_vector_type(8))) short bf16x8;
typedef __attribute__((ext_vector_type(4))) float f32x4;
typedef __attribute__((ext_vector_type(2))) float f32x2;

// round-to-nearest-even f32 -> bf16
__device__ __forceinline__ u16 f2bf(float f) {
    u32 u = __builtin_bit_cast(u32, f);
    return (u16)((u + 0x7FFFu + ((u >> 16) & 1u)) >> 16);
}
__device__ __forceinline__ float bflo(u32 u) { return __builtin_bit_cast(float, u << 16); }
__device__ __forceinline__ float bfhi(u32 u) { return __builtin_bit_cast(float, u & 0xFFFF0000u); }
// fp16 pair <-> f32 pair
__device__ __forceinline__ float2 h2f2(u32 u) {
    __half2 h = __builtin_bit_cast(__half2, u);
    return __half22float2(h);
}
__device__ __forceinline__ u32 f2h2(float a, float b) {
    __half2 h = __floats2half2_rn(a, b);
    return __builtin_bit_cast(u32, h);
}

// ---------------------------------------------------------------------------
// W prep: Wt[n][k] = bf16(W[k][n]), both 128x128. 2 matrices.
// ---------------------------------------------------------------------------
__global__ __launch_bounds__(256) void wprep(
    const float* __restrict__ Wq, const float* __restrict__ Wk,
    u16* __restrict__ Wqt, u16* __restrict__ Wkt)
{
    int e   = blockIdx.x * 256 + threadIdx.x;
    int mat = e >> 14;
    int idx = e & 16383;
    int k  = idx >> 7;
    int nn = idx & 127;
    const float* W = mat ? Wk : Wq;
    u16*        Wt = mat ? Wkt : Wqt;
    Wt[nn * 128 + k] = f2bf(W[idx]);
}

// ---------------------------------------------------------------------------
// MFMA Q/K projection. blockIdx.y = matrix (0:Q -> qb bf16, 1:K -> k8 fp8).
// r14 post-mortem: per-element scatter stores (72 narrow VMEM stores/thread)
// at 3 blocks/CU made this store-latency-bound (46us, VALU 6.5%, occ 22%).
// Fix: stage the 64x128 output tile in LDS, flush with coalesced uint4
// stores (12 VMEM stores/thread); mat-split doubles block count (occupancy).
// mat0 blocks also emit xh (fp16 master) + x8 (fp8 gather copy).
// ---------------------------------------------------------------------------
__global__ __launch_bounds__(256) void gemm_qk_mfma(
    const float* __restrict__ x,
    const u16* __restrict__ Wqt, const float* __restrict__ bq,
    const u16* __restrict__ Wkt, const float* __restrict__ bk,
    u16* __restrict__ qb, u8* __restrict__ k8,
    u16* __restrict__ xh, u8* __restrict__ x8, int n)
{
    __shared__ __align__(16) u16 sT[64][128];   // 16 KB tile stage

    const int t  = threadIdx.x;
    const int l  = t & 63;
    const int w  = t >> 6;
    const int lr = l & 15;
    const int kg = l >> 4;
    const int mat = blockIdx.y;

    const int row0   = blockIdx.x * 64;
    const int arow   = row0 + w * 16 + lr;
    const bool av    = (arow < n);
    const int  arowc = av ? arow : (n - 1);

    bf16x8 afrag[4];
    #pragma unroll
    for (int ks = 0; ks < 4; ++ks) {
        const float* px = x + (size_t)arowc * HID + ks * 32 + kg * 8;
        float4 p0 = *(const float4*)px;
        float4 p1 = *(const float4*)(px + 4);
        uint4 pk;
        pk.x = (u32)f2bf(p0.x) | ((u32)f2bf(p0.y) << 16);
        pk.y = (u32)f2bf(p0.z) | ((u32)f2bf(p0.w) << 16);
        pk.z = (u32)f2bf(p1.x) | ((u32)f2bf(p1.y) << 16);
        pk.w = (u32)f2bf(p1.z) | ((u32)f2bf(p1.w) << 16);
        afrag[ks] = __builtin_bit_cast(bf16x8, pk);
        if (mat == 0 && av) {
            uint4 ph;
            ph.x = f2h2(p0.x, p0.y);
            ph.y = f2h2(p0.z, p0.w);
            ph.z = f2h2(p1.x, p1.y);
            ph.w = f2h2(p1.z, p1.w);
            *(uint4*)(xh + (size_t)arow * HID + ks * 32 + kg * 8) = ph;
            u32 w0 = __builtin_amdgcn_cvt_pk_fp8_f32(p0.x, p0.y, 0u, false);
            w0     = __builtin_amdgcn_cvt_pk_fp8_f32(p0.z, p0.w, w0, true);
            u32 w1 = __builtin_amdgcn_cvt_pk_fp8_f32(p1.x, p1.y, 0u, false);
            w1     = __builtin_amdgcn_cvt_pk_fp8_f32(p1.z, p1.w, w1, true);
            uint2 pv; pv.x = w0; pv.y = w1;
            *(uint2*)(x8 + (size_t)arow * HID + ks * 32 + kg * 8) = pv;
        }
    }

    const u16*   Wt   = mat ? Wkt : Wqt;
    const float* bias = mat ? bk : bq;

    #pragma unroll
    for (int cb = 0; cb < 8; ++cb) {
        float bc = bias[cb * 16 + lr];
        f32x4 acc = {bc, bc, bc, bc};
        #pragma unroll
        for (int ks = 0; ks < 4; ++ks) {
            bf16x8 bfrag = __builtin_bit_cast(bf16x8,
                *(const uint4*)(Wt + (size_t)(cb * 16 + lr) * 128 + ks * 32 + kg * 8));
            acc = __builtin_amdgcn_mfma_f32_16x16x32_bf16(afrag[ks], bfrag, acc, 0, 0, 0);
        }
        #pragma unroll
        for (int reg = 0; reg < 4; ++reg) {
            int lrow = w * 16 + kg * 4 + reg;        // tile row 0..63
            if (mat == 0) {
                sT[lrow][cb * 16 + lr] = f2bf(acc[reg]);
            } else {
                u32 p8 = __builtin_amdgcn_cvt_pk_fp8_f32(acc[reg], 0.f, 0u, false);
                ((u8*)sT)[lrow * 128 + cb * 16 + lr] = (u8)(p8 & 0xFFu);
            }
        }
    }
    __syncthreads();

    if (mat == 0) {
        // flush bf16 tile: 64 rows x 16 uint4-chunks = 1024 stores
        #pragma unroll
        for (int i = 0; i < 4; ++i) {
            int idx = i * 256 + t;
            int row = idx >> 4;
            int ch  = idx & 15;
            if (row0 + row < n)
                *(uint4*)(qb + (size_t)(row0 + row) * HID + ch * 8) =
                    *(const uint4*)&sT[row][ch * 8];
        }
    } else {
        // flush fp8 tile: 64 rows x 8 uint4-chunks = 512 stores
        #pragma unroll
        for (int i = 0; i < 2; ++i) {
            int idx = i * 256 + t;
            int row = idx >> 3;
            int ch  = idx & 7;
            if (row0 + row < n)
                *(uint4*)(k8 + (size_t)(row0 + row) * HID + ch * 16) =
                    *(const uint4*)((const u8*)sT + row * 128 + ch * 16);
        }
    }
}

// ---------------------------------------------------------------------------
// out-degree histogram over src
// ---------------------------------------------------------------------------
__global__ __launch_bounds__(256) void hist_kernel(
    const int* __restrict__ ei, int* __restrict__ deg)
{
    int i = blockIdx.x * 256 + threadIdx.x;
    if (i < EDGES) atomicAdd(&deg[ei[i]], 1);
}

// ---------------------------------------------------------------------------
// two-level exclusive scan of deg -> off; also emits bucket cursors
// ---------------------------------------------------------------------------
__global__ __launch_bounds__(1024) void scan1(
    const int* __restrict__ deg, int* __restrict__ off,
    int* __restrict__ part, int n)
{
    __shared__ int sd[1024];
    int t = threadIdx.x, i = blockIdx.x * 1024 + t;
    int v = (i < n) ? deg[i] : 0;
    sd[t] = v;
    __syncthreads();
    #pragma unroll
    for (int o = 1; o < 1024; o <<= 1) {
        int a = (t >= o) ? sd[t - o] : 0;
        __syncthreads();
        sd[t] += a;
        __syncthreads();
    }
    if (i < n) off[i] = sd[t] - v;
    if (t == 1023) part[blockIdx.x] = sd[1023];
}

__global__ __launch_bounds__(64) void scan2(int* __restrict__ part,
                                            int* __restrict__ off_n, int nb)
{
    int t = threadIdx.x;
    int v = (t < nb) ? part[t] : 0;
    int orig = v;
    #pragma unroll
    for (int o = 1; o < 64; o <<= 1) {
        int a = __shfl_up(v, o);
        if (t >= o) v += a;
    }
    if (t < nb) part[t] = v - orig;
    if (t == 63) *off_n = v;
}

__global__ __launch_bounds__(1024) void scan3(
    int* __restrict__ off, int* __restrict__ bcur,
    const int* __restrict__ part, int n)
{
    int i = blockIdx.x * 1024 + threadIdx.x;
    if (i < n) {
        int o = off[i] + part[blockIdx.x];
        off[i] = o;
        if ((i & 255) == 0) bcur[i >> 8] = o;   // bucket base cursor
    }
}

// ---------------------------------------------------------------------------
// Phase 1: bin edges by bucket (src>>8) into tmp, bucket-contiguous.
// ---------------------------------------------------------------------------
__global__ __launch_bounds__(256) void bin_edges(
    const int* __restrict__ ei, int* __restrict__ bcur, u32* __restrict__ tmp)
{
    __shared__ u32 buf[CHUNK];
    __shared__ int hist[NBUCK];
    __shared__ int lcur[NBUCK];

    const int t  = threadIdx.x;
    const int e0 = blockIdx.x * CHUNK;
    const int e1 = (e0 + CHUNK < EDGES) ? e0 + CHUNK : EDGES;
    const int cnt = e1 - e0;

    for (int b = t; b < NBUCK; b += 256) hist[b] = 0;
    __syncthreads();

    for (int i = t; i < cnt; i += 256) {
        int src = ei[e0 + i];
        int dst = ei[EDGES + e0 + i];
        buf[i] = (u32)dst | ((u32)(src & 255) << 16) | ((u32)(src >> 8) << 24);
        atomicAdd(&hist[src >> 8], 1);
    }
    __syncthreads();

    for (int b = t; b < NBUCK; b += 256) {
        int h = hist[b];
        lcur[b] = h ? atomicAdd(&bcur[b], h) : 0;
    }
    __syncthreads();

    for (int i = t; i < cnt; i += 256) {
        u32 pk  = buf[i];
        int b   = pk >> 24;
        int pos = atomicAdd(&lcur[b], 1);
        tmp[pos] = pk & 0x00FFFFFFu;          // srcLocal<<16 | dst
    }
}

// ---------------------------------------------------------------------------
// Phase 2: exact CSR placement within each bucket (LDS cursors, local window)
// ---------------------------------------------------------------------------
__global__ __launch_bounds__(256) void place_edges(
    const u32* __restrict__ tmp, const int* __restrict__ off,
    u32* __restrict__ epack, int n)
{
    __shared__ int lcur[256];
    const int t     = threadIdx.x;
    const int nbase = blockIdx.x << 8;
    const int nend  = (nbase + 256 < n) ? nbase + 256 : n;

    if (nbase + t < nend) lcur[t] = off[nbase + t];
    __syncthreads();

    const int s0 = off[nbase];
    const int s1 = off[nend];
    for (int i = s0 + t; i < s1; i += 256) {
        u32 pk    = tmp[i];
        int local = pk >> 16;
        int pos   = atomicAdd(&lcur[local], 1);
        epack[pos] = pk & 0xFFFFu;            // dst only (att packed later)
    }
}

// ---------------------------------------------------------------------------
// CSR-ordered scores: wave per src node, 4 groups x 16 lanes, 4-deep gather
// pipelining. q[src] bf16 loaded once; k gathered as fp8 rows (128B).
// HW decode via v_cvt_pk_f32_fp8. e-values stored packed bf16.
// ---------------------------------------------------------------------------
__global__ __launch_bounds__(256) void score_csr(
    const u16* __restrict__ qb, const u8* __restrict__ k8,
    const int* __restrict__ off, const u32* __restrict__ ccol,
    u16* __restrict__ evals16, float* __restrict__ nsum, int n)
{
    const int wv   = (blockIdx.x * 256 + threadIdx.x) >> 6;   // src node
    const int lane = threadIdx.x & 63;
    const int l16  = lane & 15;
    const int grp  = lane >> 4;
    if (wv >= n) return;

    const int beg = off[wv];
    const int end = off[wv + 1];

    uint4 qv = *(const uint4*)(qb + (size_t)wv * HID + l16 * 8);

    for (int j = beg; j < end; j += 16) {
        u32 d[4]; u64 kv[4];
        #pragma unroll
        for (int u = 0; u < 4; ++u) {
            int e  = j + grp + u * 4;
            int ec = (e < end) ? e : (end - 1);
            d[u] = ccol[ec];
        }
        #pragma unroll
        for (int u = 0; u < 4; ++u)
            kv[u] = *(const u64*)(k8 + (size_t)d[u] * HID + l16 * 8);
        #pragma unroll
        for (int u = 0; u < 4; ++u) {
            int e = j + grp + u * 4;
            u32 klo = (u32)kv[u], khi = (u32)(kv[u] >> 32);
            f32x2 a = __builtin_amdgcn_cvt_pk_f32_fp8(klo, false);
            f32x2 b = __builtin_amdgcn_cvt_pk_f32_fp8(klo, true);
            f32x2 c = __builtin_amdgcn_cvt_pk_f32_fp8(khi, false);
            f32x2 dd= __builtin_amdgcn_cvt_pk_f32_fp8(khi, true);
            float p = bflo(qv.x) * a.x + bfhi(qv.x) * a.y
                    + bflo(qv.y) * b.x + bfhi(qv.y) * b.y
                    + bflo(qv.z) * c.x + bfhi(qv.z) * c.y
                    + bflo(qv.w) * dd.x + bfhi(qv.w) * dd.y;
            p += __shfl_xor(p, 1);
            p += __shfl_xor(p, 2);
            if (e < end && (l16 & 3) == 0) {
                int head = l16 >> 2;
                float ev = __expf(p * SCORE_SCALE);
                evals16[(size_t)e * HEADS + head] = f2bf(ev);
                atomicAdd(&nsum[(size_t)d[u] * HEADS + head], ev);
            }
        }
    }
}

// ---------------------------------------------------------------------------
// head-mean attention; packs epack[pos] = dst | bf16(att)<<16 IN PLACE.
// ---------------------------------------------------------------------------
__global__ __launch_bounds__(256) void finalize_kernel(
    const u16* __restrict__ evals16, const float* __restrict__ nsum,
    u32* __restrict__ epack)
{
    int pos = blockIdx.x * 256 + threadIdx.x;
    if (pos >= EDGES) return;
    u32 dst = epack[pos];
    u64 ev8 = *(const u64*)(evals16 + (size_t)pos * HEADS);
    u32 lo = (u32)ev8, hi = (u32)(ev8 >> 32);
    float4 sv = *(const float4*)(nsum + (size_t)dst * HEADS);
    float am = 0.25f * (bflo(lo) / (sv.x + 1e-16f) + bfhi(lo) / (sv.y + 1e-16f) +
                        bflo(hi) / (sv.z + 1e-16f) + bfhi(hi) / (sv.w + 1e-16f));
    epack[pos] = dst | ((u32)f2bf(am) << 16);
}

// ---------------------------------------------------------------------------
// SCALARIZED Euler step with fp8 gathers. Master state fp16 (never quantized
// to fp8 -- only the gathered COPY is fp8). Gathered row = 128B. Node w is
// wave-uniform -> epack loads scalar (r13). Decode: v_cvt_pk_f32_fp8.
// NOTE (r7): keep wave count high; (r12): keep VGPR low for occupancy.
// ---------------------------------------------------------------------------
template<int FINAL>
__global__ __launch_bounds__(256) void spmv_h8(
    const u16* __restrict__ inh, const u8* __restrict__ in8,
    u16* __restrict__ outh, u8* __restrict__ out8,
    float* __restrict__ outf,
    const int* __restrict__ off, const u32* __restrict__ epack, int n)
{
    const int w    = (blockIdx.x * 256 + threadIdx.x) >> 6;
    const int lane = threadIdx.x & 63;
    if (w >= n) return;

    const int beg = __builtin_amdgcn_readfirstlane(off[w]);
    const int end = __builtin_amdgcn_readfirstlane(off[w + 1]);

    const u16* in8w = (const u16*)in8;         // 64 fp8-pairs per 128-dim row

    float ax = 0.f, ay = 0.f;
    int j = beg;
    for (; j + 8 <= end; j += 8) {
        u32 e[8], s[8];
        #pragma unroll
        for (int u = 0; u < 8; ++u) e[u] = epack[j + u];          // uniform -> SGPR
        #pragma unroll
        for (int u = 0; u < 8; ++u)
            s[u] = in8w[(size_t)(e[u] & 0xFFFFu) * 64 + lane];    // 2B/lane gather
        #pragma unroll
        for (int u = 0; u < 8; ++u) {
            float vv = bfhi(e[u]);
            f32x2 sv = __builtin_amdgcn_cvt_pk_f32_fp8(s[u], false);
            ax += vv * sv.x;
            ay += vv * sv.y;
        }
    }
    for (; j + 4 <= end; j += 4) {
        u32 e[4], s[4];
        #pragma unroll
        for (int u = 0; u < 4; ++u) e[u] = epack[j + u];
        #pragma unroll
        for (int u = 0; u < 4; ++u)
            s[u] = in8w[(size_t)(e[u] & 0xFFFFu) * 64 + lane];
        #pragma unroll
        for (int u = 0; u < 4; ++u) {
            float vv = bfhi(e[u]);
            f32x2 sv = __builtin_amdgcn_cvt_pk_f32_fp8(s[u], false);
            ax += vv * sv.x;
            ay += vv * sv.y;
        }
    }
    for (; j < end; ++j) {
        u32 e = epack[j];
        u32 s = in8w[(size_t)(e & 0xFFFFu) * 64 + lane];
        float vv = bfhi(e);
        f32x2 sv = __builtin_amdgcn_cvt_pk_f32_fp8(s, false);
        ax += vv * sv.x;
        ay += vv * sv.y;
    }

    // own row from fp16 MASTER (full precision path)
    u32 zi = *(const u32*)(inh + (size_t)w * HID + lane * 2);
    float2 xi = h2f2(zi);
    const float ox = 0.75f * xi.x + 0.25f * ax;
    const float oy = 0.75f * xi.y + 0.25f * ay;
    if (FINAL) {
        float2 o; o.x = ox; o.y = oy;
        *(float2*)(outf + (size_t)w * HID + lane * 2) = o;
    } else {
        *(u32*)(outh + (size_t)w * HID + lane * 2) = f2h2(ox, oy);
        u32 p8 = __builtin_amdgcn_cvt_pk_fp8_f32(ox, oy, 0u, false);
        ((u16*)out8)[(size_t)w * 64 + lane] = (u16)(p8 & 0xFFFFu);
    }
}

// ---------------------------------------------------------------------------
extern "C" void kernel_launch(void* const* d_in, const int* in_sizes, int n_in,
                              void* d_out, int out_size, void* d_ws, size_t ws_size,
                              hipStream_t stream)
{
    (void)in_sizes; (void)n_in; (void)out_size; (void)ws_size;

    const float* x  = (const float*)d_in[0];
    const float* Wq = (const float*)d_in[1];
    const float* bq = (const float*)d_in[2];
    const float* Wk = (const float*)d_in[3];
    const float* bk = (const float*)d_in[4];
    const int*   ei = (const int*)d_in[5];
    float* out = (float*)d_out;

    const int N = NODES, E = EDGES;
    const size_t ROWB_H = (size_t)N * HID * 2;   // 12.8 MB fp16 state
    const size_t ROWB_8 = (size_t)N * HID;       //  6.4 MB fp8 state

    char* ws = (char*)d_ws;
    // qb (dead after score) overlaid with z2h; k8 (dead after score) with z28
    u16*   qb   = (u16*)ws;
    u16*   z2h  = (u16*)ws;  ws += ROWB_H;
    u8*    k8   = (u8*)ws;
    u8*    z28  = (u8*)ws;   ws += ROWB_8;
    // xh/x8 (dead after spmv step 1) overlaid with z3h/z38
    u16*   xh   = (u16*)ws;
    u16*   z3h  = (u16*)ws;  ws += ROWB_H;
    u8*    x8   = (u8*)ws;
    u8*    z38  = (u8*)ws;   ws += ROWB_8;
    // evals16 (dead after finalize) overlaid with z18
    u16*   evals16 = (u16*)ws;
    u8*    z18  = (u8*)ws;   ws += (size_t)E * HEADS * 2;   // 6.4 MB
    u16*   z1h  = (u16*)ws;  ws += ROWB_H;
    float* nsum = (float*)ws; ws += (size_t)N * HEADS * 4;
    int*   deg  = (int*)ws;   ws += (size_t)N * 4;
    int*   off  = (int*)ws;   ws += ((size_t)(N + 1) * 4 + 255) & ~255ull;
    int*   bcur = (int*)ws;   ws += ((size_t)NBUCK * 4 + 255) & ~255ull;
    int*   part = (int*)ws;   ws += 256;
    u32*   epack = (u32*)ws;  ws += (size_t)E * 4;   // dst-only CSR, then packed
    u32*   tmp   = (u32*)ws;  ws += (size_t)E * 4;   // bucket-grouped edges
    u16*   Wqt   = (u16*)ws;  ws += (size_t)128 * 128 * 2;
    u16*   Wkt   = (u16*)ws;  ws += (size_t)128 * 128 * 2;

    // zero nsum + deg (contiguous)
    hipMemsetAsync(nsum, 0, (size_t)N * HEADS * 4 + (size_t)N * 4, stream);

    // W -> bf16 transposed
    wprep<<<128, 256, 0, stream>>>(Wq, Wk, Wqt, Wkt);

    // Q/K projections via MFMA (LDS-staged coalesced stores, mat-split grid)
    gemm_qk_mfma<<<dim3((N + 63) / 64, 2), 256, 0, stream>>>(
        x, Wqt, bq, Wkt, bk, qb, k8, xh, x8, N);

    // degree histogram (by src)
    hist_kernel<<<E / 256, 256, 0, stream>>>(ei, deg);

    // CSR offsets: two-level scan (+ bucket cursors)
    const int nb = (N + 1023) / 1024;
    scan1<<<nb, 1024, 0, stream>>>(deg, off, part, N);
    scan2<<<1, 64, 0, stream>>>(part, off + N, nb);
    scan3<<<nb, 1024, 0, stream>>>(off, bcur, part, N);

    // two-phase binned CSR fill
    bin_edges<<<(E + CHUNK - 1) / CHUNK, 256, 0, stream>>>(ei, bcur, tmp);
    place_edges<<<NBUCK, 256, 0, stream>>>(tmp, off, epack, N);

    // CSR-ordered scores (fp8 k gathers) -> exp (bf16) -> segment sums
    score_csr<<<(N * 64 + 255) / 256, 256, 0, stream>>>(
        qb, k8, off, epack, evals16, nsum, N);

    // attention mean, packed in place
    finalize_kernel<<<E / 256, 256, 0, stream>>>(evals16, nsum, epack);

    // 4 Euler steps: fp16 master chain + fp8 gather copies
    const int sg = (N * 64 + 255) / 256;
    spmv_h8<0><<<sg, 256, 0, stream>>>(xh,  x8,  z1h, z18, nullptr, off, epack, N);
    spmv_h8<0><<<sg, 256, 0, stream>>>(z1h, z18, z2h, z28, nullptr, off, epack, N);
    spmv_h8<0><<<sg, 256, 0, stream>>>(z2h, z28, z3h, z38, nullptr, off, epack, N);
    spmv_h8<1><<<sg, 256, 0, stream>>>(z3h, z38, nullptr, nullptr, out, off, epack, N);
}

// Round 16
// 260.538 us; speedup vs baseline: 1.3530x; 1.0091x over previous
//
#include <hip/hip_runtime.h>
#include <hip/hip_fp16.h>

#define NODES 50000
#define EDGES 800000
#define HID   128
#define HEADS 4
// DK = 32, scale = 1/sqrt(32)
#define SCORE_SCALE 0.17677669529663687f

#define NBUCK ((NODES + 255) >> 8)   // 196 buckets of 256 src nodes
#define CHUNK 4096

typedef unsigned int       u32;
typedef unsigned short     u16;
typedef unsigned char      u8;
typedef unsigned long long u64;

typedef __attribute__((ext_vector_type(8))) short bf16x8;
typedef __attribute__((ext_vector_type(4))) float f32x4;
typedef __attribute__((ext_vector_type(2))) float f32x2;

// round-to-nearest-even f32 -> bf16
__device__ __forceinline__ u16 f2bf(float f) {
    u32 u = __builtin_bit_cast(u32, f);
    return (u16)((u + 0x7FFFu + ((u >> 16) & 1u)) >> 16);
}
__device__ __forceinline__ float bflo(u32 u) { return __builtin_bit_cast(float, u << 16); }
__device__ __forceinline__ float bfhi(u32 u) { return __builtin_bit_cast(float, u & 0xFFFF0000u); }
// fp16 pair <-> f32 pair
__device__ __forceinline__ float2 h2f2(u32 u) {
    __half2 h = __builtin_bit_cast(__half2, u);
    return __half22float2(h);
}
__device__ __forceinline__ u32 f2h2(float a, float b) {
    __half2 h = __floats2half2_rn(a, b);
    return __builtin_bit_cast(u32, h);
}

// ---------------------------------------------------------------------------
// W prep: Wt[n][k] = bf16(W[k][n]), both 128x128. 2 matrices.
// ---------------------------------------------------------------------------
__global__ __launch_bounds__(256) void wprep(
    const float* __restrict__ Wq, const float* __restrict__ Wk,
    u16* __restrict__ Wqt, u16* __restrict__ Wkt)
{
    int e   = blockIdx.x * 256 + threadIdx.x;
    int mat = e >> 14;
    int idx = e & 16383;
    int k  = idx >> 7;
    int nn = idx & 127;
    const float* W = mat ? Wk : Wq;
    u16*        Wt = mat ? Wkt : Wqt;
    Wt[nn * 128 + k] = f2bf(W[idx]);
}

// ---------------------------------------------------------------------------
// MFMA Q/K projection. blockIdx.y = matrix (0:Q -> qb bf16, 1:K -> k8 fp8).
// LDS-staged coalesced stores (r15); mat-split grid for occupancy.
// mat0 blocks also emit xh (fp16 master) + x8 (fp8 gather copy).
// ---------------------------------------------------------------------------
__global__ __launch_bounds__(256) void gemm_qk_mfma(
    const float* __restrict__ x,
    const u16* __restrict__ Wqt, const float* __restrict__ bq,
    const u16* __restrict__ Wkt, const float* __restrict__ bk,
    u16* __restrict__ qb, u8* __restrict__ k8,
    u16* __restrict__ xh, u8* __restrict__ x8, int n)
{
    __shared__ __align__(16) u16 sT[64][128];   // 16 KB tile stage

    const int t  = threadIdx.x;
    const int l  = t & 63;
    const int w  = t >> 6;
    const int lr = l & 15;
    const int kg = l >> 4;
    const int mat = blockIdx.y;

    const int row0   = blockIdx.x * 64;
    const int arow   = row0 + w * 16 + lr;
    const bool av    = (arow < n);
    const int  arowc = av ? arow : (n - 1);

    bf16x8 afrag[4];
    #pragma unroll
    for (int ks = 0; ks < 4; ++ks) {
        const float* px = x + (size_t)arowc * HID + ks * 32 + kg * 8;
        float4 p0 = *(const float4*)px;
        float4 p1 = *(const float4*)(px + 4);
        uint4 pk;
        pk.x = (u32)f2bf(p0.x) | ((u32)f2bf(p0.y) << 16);
        pk.y = (u32)f2bf(p0.z) | ((u32)f2bf(p0.w) << 16);
        pk.z = (u32)f2bf(p1.x) | ((u32)f2bf(p1.y) << 16);
        pk.w = (u32)f2bf(p1.z) | ((u32)f2bf(p1.w) << 16);
        afrag[ks] = __builtin_bit_cast(bf16x8, pk);
        if (mat == 0 && av) {
            uint4 ph;
            ph.x = f2h2(p0.x, p0.y);
            ph.y = f2h2(p0.z, p0.w);
            ph.z = f2h2(p1.x, p1.y);
            ph.w = f2h2(p1.z, p1.w);
            *(uint4*)(xh + (size_t)arow * HID + ks * 32 + kg * 8) = ph;
            u32 w0 = __builtin_amdgcn_cvt_pk_fp8_f32(p0.x, p0.y, 0u, false);
            w0     = __builtin_amdgcn_cvt_pk_fp8_f32(p0.z, p0.w, w0, true);
            u32 w1 = __builtin_amdgcn_cvt_pk_fp8_f32(p1.x, p1.y, 0u, false);
            w1     = __builtin_amdgcn_cvt_pk_fp8_f32(p1.z, p1.w, w1, true);
            uint2 pv; pv.x = w0; pv.y = w1;
            *(uint2*)(x8 + (size_t)arow * HID + ks * 32 + kg * 8) = pv;
        }
    }

    const u16*   Wt   = mat ? Wkt : Wqt;
    const float* bias = mat ? bk : bq;

    #pragma unroll
    for (int cb = 0; cb < 8; ++cb) {
        float bc = bias[cb * 16 + lr];
        f32x4 acc = {bc, bc, bc, bc};
        #pragma unroll
        for (int ks = 0; ks < 4; ++ks) {
            bf16x8 bfrag = __builtin_bit_cast(bf16x8,
                *(const uint4*)(Wt + (size_t)(cb * 16 + lr) * 128 + ks * 32 + kg * 8));
            acc = __builtin_amdgcn_mfma_f32_16x16x32_bf16(afrag[ks], bfrag, acc, 0, 0, 0);
        }
        #pragma unroll
        for (int reg = 0; reg < 4; ++reg) {
            int lrow = w * 16 + kg * 4 + reg;        // tile row 0..63
            if (mat == 0) {
                sT[lrow][cb * 16 + lr] = f2bf(acc[reg]);
            } else {
                u32 p8 = __builtin_amdgcn_cvt_pk_fp8_f32(acc[reg], 0.f, 0u, false);
                ((u8*)sT)[lrow * 128 + cb * 16 + lr] = (u8)(p8 & 0xFFu);
            }
        }
    }
    __syncthreads();

    if (mat == 0) {
        #pragma unroll
        for (int i = 0; i < 4; ++i) {
            int idx = i * 256 + t;
            int row = idx >> 4;
            int ch  = idx & 15;
            if (row0 + row < n)
                *(uint4*)(qb + (size_t)(row0 + row) * HID + ch * 8) =
                    *(const uint4*)&sT[row][ch * 8];
        }
    } else {
        #pragma unroll
        for (int i = 0; i < 2; ++i) {
            int idx = i * 256 + t;
            int row = idx >> 3;
            int ch  = idx & 7;
            if (row0 + row < n)
                *(uint4*)(k8 + (size_t)(row0 + row) * HID + ch * 16) =
                    *(const uint4*)((const u8*)sT + row * 128 + ch * 16);
        }
    }
}

// ---------------------------------------------------------------------------
// out-degree histogram over src
// ---------------------------------------------------------------------------
__global__ __launch_bounds__(256) void hist_kernel(
    const int* __restrict__ ei, int* __restrict__ deg)
{
    int i = blockIdx.x * 256 + threadIdx.x;
    if (i < EDGES) atomicAdd(&deg[ei[i]], 1);
}

// ---------------------------------------------------------------------------
// two-level exclusive scan of deg -> off; also emits bucket cursors
// ---------------------------------------------------------------------------
__global__ __launch_bounds__(1024) void scan1(
    const int* __restrict__ deg, int* __restrict__ off,
    int* __restrict__ part, int n)
{
    __shared__ int sd[1024];
    int t = threadIdx.x, i = blockIdx.x * 1024 + t;
    int v = (i < n) ? deg[i] : 0;
    sd[t] = v;
    __syncthreads();
    #pragma unroll
    for (int o = 1; o < 1024; o <<= 1) {
        int a = (t >= o) ? sd[t - o] : 0;
        __syncthreads();
        sd[t] += a;
        __syncthreads();
    }
    if (i < n) off[i] = sd[t] - v;
    if (t == 1023) part[blockIdx.x] = sd[1023];
}

__global__ __launch_bounds__(64) void scan2(int* __restrict__ part,
                                            int* __restrict__ off_n, int nb)
{
    int t = threadIdx.x;
    int v = (t < nb) ? part[t] : 0;
    int orig = v;
    #pragma unroll
    for (int o = 1; o < 64; o <<= 1) {
        int a = __shfl_up(v, o);
        if (t >= o) v += a;
    }
    if (t < nb) part[t] = v - orig;
    if (t == 63) *off_n = v;
}

__global__ __launch_bounds__(1024) void scan3(
    int* __restrict__ off, int* __restrict__ bcur,
    const int* __restrict__ part, int n)
{
    int i = blockIdx.x * 1024 + threadIdx.x;
    if (i < n) {
        int o = off[i] + part[blockIdx.x];
        off[i] = o;
        if ((i & 255) == 0) bcur[i >> 8] = o;   // bucket base cursor
    }
}

// ---------------------------------------------------------------------------
// Phase 1: bin edges by bucket (src>>8) into tmp, bucket-contiguous.
// ---------------------------------------------------------------------------
__global__ __launch_bounds__(256) void bin_edges(
    const int* __restrict__ ei, int* __restrict__ bcur, u32* __restrict__ tmp)
{
    __shared__ u32 buf[CHUNK];
    __shared__ int hist[NBUCK];
    __shared__ int lcur[NBUCK];

    const int t  = threadIdx.x;
    const int e0 = blockIdx.x * CHUNK;
    const int e1 = (e0 + CHUNK < EDGES) ? e0 + CHUNK : EDGES;
    const int cnt = e1 - e0;

    for (int b = t; b < NBUCK; b += 256) hist[b] = 0;
    __syncthreads();

    for (int i = t; i < cnt; i += 256) {
        int src = ei[e0 + i];
        int dst = ei[EDGES + e0 + i];
        buf[i] = (u32)dst | ((u32)(src & 255) << 16) | ((u32)(src >> 8) << 24);
        atomicAdd(&hist[src >> 8], 1);
    }
    __syncthreads();

    for (int b = t; b < NBUCK; b += 256) {
        int h = hist[b];
        lcur[b] = h ? atomicAdd(&bcur[b], h) : 0;
    }
    __syncthreads();

    for (int i = t; i < cnt; i += 256) {
        u32 pk  = buf[i];
        int b   = pk >> 24;
        int pos = atomicAdd(&lcur[b], 1);
        tmp[pos] = pk & 0x00FFFFFFu;          // srcLocal<<16 | dst
    }
}

// ---------------------------------------------------------------------------
// Phase 2: exact CSR placement within each bucket (LDS cursors, local window)
// ---------------------------------------------------------------------------
__global__ __launch_bounds__(256) void place_edges(
    const u32* __restrict__ tmp, const int* __restrict__ off,
    u32* __restrict__ epack, int n)
{
    __shared__ int lcur[256];
    const int t     = threadIdx.x;
    const int nbase = blockIdx.x << 8;
    const int nend  = (nbase + 256 < n) ? nbase + 256 : n;

    if (nbase + t < nend) lcur[t] = off[nbase + t];
    __syncthreads();

    const int s0 = off[nbase];
    const int s1 = off[nend];
    for (int i = s0 + t; i < s1; i += 256) {
        u32 pk    = tmp[i];
        int local = pk >> 16;
        int pos   = atomicAdd(&lcur[local], 1);
        epack[pos] = pk & 0xFFFFu;            // dst only (att packed later)
    }
}

// ---------------------------------------------------------------------------
// CSR-ordered scores, SOFTWARE-PIPELINED index stream: the next batch's
// ccol indices are loaded WHILE the current batch's k8 gathers are in
// flight (r15 diagnosis: per-batch critical path = index-load round-trip +
// gather round-trip, serialized; overlap removes the first).
// Wave per src node, 4 groups x 16 lanes; q[src] bf16 loaded once;
// k gathered as fp8 rows. Math identical to r15.
// ---------------------------------------------------------------------------
__global__ __launch_bounds__(256) void score_csr(
    const u16* __restrict__ qb, const u8* __restrict__ k8,
    const int* __restrict__ off, const u32* __restrict__ ccol,
    u16* __restrict__ evals16, float* __restrict__ nsum, int n)
{
    const int wv   = (blockIdx.x * 256 + threadIdx.x) >> 6;   // src node
    const int lane = threadIdx.x & 63;
    const int l16  = lane & 15;
    const int grp  = lane >> 4;
    if (wv >= n) return;

    const int beg = off[wv];
    const int end = off[wv + 1];
    if (beg >= end) return;

    uint4 qv = *(const uint4*)(qb + (size_t)wv * HID + l16 * 8);

    // preload first index batch
    u32 d[4];
    #pragma unroll
    for (int u = 0; u < 4; ++u) {
        int e  = beg + grp + u * 4;
        int ec = (e < end) ? e : (end - 1);
        d[u] = ccol[ec];
    }

    for (int j = beg; j < end; j += 16) {
        // issue current gathers
        u64 kv[4];
        #pragma unroll
        for (int u = 0; u < 4; ++u)
            kv[u] = *(const u64*)(k8 + (size_t)d[u] * HID + l16 * 8);

        // prefetch next index batch (overlaps gather latency)
        u32 dn[4];
        #pragma unroll
        for (int u = 0; u < 4; ++u) {
            int e  = j + 16 + grp + u * 4;
            int ec = (e < end) ? e : (end - 1);
            dn[u] = ccol[ec];
        }

        #pragma unroll
        for (int u = 0; u < 4; ++u) {
            int e = j + grp + u * 4;
            u32 klo = (u32)kv[u], khi = (u32)(kv[u] >> 32);
            f32x2 a = __builtin_amdgcn_cvt_pk_f32_fp8(klo, false);
            f32x2 b = __builtin_amdgcn_cvt_pk_f32_fp8(klo, true);
            f32x2 c = __builtin_amdgcn_cvt_pk_f32_fp8(khi, false);
            f32x2 dd= __builtin_amdgcn_cvt_pk_f32_fp8(khi, true);
            float p = bflo(qv.x) * a.x + bfhi(qv.x) * a.y
                    + bflo(qv.y) * b.x + bfhi(qv.y) * b.y
                    + bflo(qv.z) * c.x + bfhi(qv.z) * c.y
                    + bflo(qv.w) * dd.x + bfhi(qv.w) * dd.y;
            p += __shfl_xor(p, 1);
            p += __shfl_xor(p, 2);
            if (e < end && (l16 & 3) == 0) {
                int head = l16 >> 2;
                float ev = __expf(p * SCORE_SCALE);
                evals16[(size_t)e * HEADS + head] = f2bf(ev);
                atomicAdd(&nsum[(size_t)d[u] * HEADS + head], ev);
            }
        }

        #pragma unroll
        for (int u = 0; u < 4; ++u) d[u] = dn[u];
    }
}

// ---------------------------------------------------------------------------
// head-mean attention; packs epack[pos] = dst | bf16(att)<<16 IN PLACE.
// ---------------------------------------------------------------------------
__global__ __launch_bounds__(256) void finalize_kernel(
    const u16* __restrict__ evals16, const float* __restrict__ nsum,
    u32* __restrict__ epack)
{
    int pos = blockIdx.x * 256 + threadIdx.x;
    if (pos >= EDGES) return;
    u32 dst = epack[pos];
    u64 ev8 = *(const u64*)(evals16 + (size_t)pos * HEADS);
    u32 lo = (u32)ev8, hi = (u32)(ev8 >> 32);
    float4 sv = *(const float4*)(nsum + (size_t)dst * HEADS);
    float am = 0.25f * (bflo(lo) / (sv.x + 1e-16f) + bfhi(lo) / (sv.y + 1e-16f) +
                        bflo(hi) / (sv.z + 1e-16f) + bfhi(hi) / (sv.w + 1e-16f));
    epack[pos] = dst | ((u32)f2bf(am) << 16);
}

// ---------------------------------------------------------------------------
// SCALARIZED + SOFTWARE-PIPELINED Euler step with fp8 gathers.
// Node w wave-uniform -> epack values live in SGPRs (r13). NEW (r16): the
// next 8-edge batch's epack loads issue WHILE the current batch's gathers
// are in flight -- the two dependent memory round-trips (index -> gather)
// that formed the per-batch critical path now overlap. Math identical.
// Master state fp16; gathered copy fp8 (128B row). Final step writes f32.
// NOTE (r7): keep wave count high; (r12): keep VGPR low for occupancy.
// ---------------------------------------------------------------------------
template<int FINAL>
__global__ __launch_bounds__(256) void spmv_h8(
    const u16* __restrict__ inh, const u8* __restrict__ in8,
    u16* __restrict__ outh, u8* __restrict__ out8,
    float* __restrict__ outf,
    const int* __restrict__ off, const u32* __restrict__ epack, int n)
{
    const int w    = (blockIdx.x * 256 + threadIdx.x) >> 6;
    const int lane = threadIdx.x & 63;
    if (w >= n) return;

    const int beg = __builtin_amdgcn_readfirstlane(off[w]);
    const int end = __builtin_amdgcn_readfirstlane(off[w + 1]);

    const u16* in8w = (const u16*)in8;         // 64 fp8-pairs per 128-dim row

    float ax = 0.f, ay = 0.f;
    int j = beg;

    if (j + 8 <= end) {
        u32 eA[8];
        #pragma unroll
        for (int u = 0; u < 8; ++u) eA[u] = epack[j + u];       // uniform -> SGPR

        for (; j + 16 <= end; j += 8) {
            // issue current gathers (addresses ready)
            u32 s[8];
            #pragma unroll
            for (int u = 0; u < 8; ++u)
                s[u] = in8w[(size_t)(eA[u] & 0xFFFFu) * 64 + lane];

            // prefetch next batch's indices (overlaps gather latency)
            u32 eB[8];
            #pragma unroll
            for (int u = 0; u < 8; ++u) eB[u] = epack[j + 8 + u];

            #pragma unroll
            for (int u = 0; u < 8; ++u) {
                float vv = bfhi(eA[u]);
                f32x2 sv = __builtin_amdgcn_cvt_pk_f32_fp8(s[u], false);
                ax += vv * sv.x;
                ay += vv * sv.y;
            }
            #pragma unroll
            for (int u = 0; u < 8; ++u) eA[u] = eB[u];
        }

        // drain the in-flight batch
        u32 s[8];
        #pragma unroll
        for (int u = 0; u < 8; ++u)
            s[u] = in8w[(size_t)(eA[u] & 0xFFFFu) * 64 + lane];
        #pragma unroll
        for (int u = 0; u < 8; ++u) {
            float vv = bfhi(eA[u]);
            f32x2 sv = __builtin_amdgcn_cvt_pk_f32_fp8(s[u], false);
            ax += vv * sv.x;
            ay += vv * sv.y;
        }
        j += 8;
    }

    // 4-deep arm for mid tails
    for (; j + 4 <= end; j += 4) {
        u32 e[4], s[4];
        #pragma unroll
        for (int u = 0; u < 4; ++u) e[u] = epack[j + u];
        #pragma unroll
        for (int u = 0; u < 4; ++u)
            s[u] = in8w[(size_t)(e[u] & 0xFFFFu) * 64 + lane];
        #pragma unroll
        for (int u = 0; u < 4; ++u) {
            float vv = bfhi(e[u]);
            f32x2 sv = __builtin_amdgcn_cvt_pk_f32_fp8(s[u], false);
            ax += vv * sv.x;
            ay += vv * sv.y;
        }
    }
    for (; j < end; ++j) {
        u32 e = epack[j];
        u32 s = in8w[(size_t)(e & 0xFFFFu) * 64 + lane];
        float vv = bfhi(e);
        f32x2 sv = __builtin_amdgcn_cvt_pk_f32_fp8(s, false);
        ax += vv * sv.x;
        ay += vv * sv.y;
    }

    // own row from fp16 MASTER (full precision path)
    u32 zi = *(const u32*)(inh + (size_t)w * HID + lane * 2);
    float2 xi = h2f2(zi);
    const float ox = 0.75f * xi.x + 0.25f * ax;
    const float oy = 0.75f * xi.y + 0.25f * ay;
    if (FINAL) {
        float2 o; o.x = ox; o.y = oy;
        *(float2*)(outf + (size_t)w * HID + lane * 2) = o;
    } else {
        *(u32*)(outh + (size_t)w * HID + lane * 2) = f2h2(ox, oy);
        u32 p8 = __builtin_amdgcn_cvt_pk_fp8_f32(ox, oy, 0u, false);
        ((u16*)out8)[(size_t)w * 64 + lane] = (u16)(p8 & 0xFFFFu);
    }
}

// ---------------------------------------------------------------------------
extern "C" void kernel_launch(void* const* d_in, const int* in_sizes, int n_in,
                              void* d_out, int out_size, void* d_ws, size_t ws_size,
                              hipStream_t stream)
{
    (void)in_sizes; (void)n_in; (void)out_size; (void)ws_size;

    const float* x  = (const float*)d_in[0];
    const float* Wq = (const float*)d_in[1];
    const float* bq = (const float*)d_in[2];
    const float* Wk = (const float*)d_in[3];
    const float* bk = (const float*)d_in[4];
    const int*   ei = (const int*)d_in[5];
    float* out = (float*)d_out;

    const int N = NODES, E = EDGES;
    const size_t ROWB_H = (size_t)N * HID * 2;   // 12.8 MB fp16 state
    const size_t ROWB_8 = (size_t)N * HID;       //  6.4 MB fp8 state

    char* ws = (char*)d_ws;
    // qb (dead after score) overlaid with z2h; k8 (dead after score) with z28
    u16*   qb   = (u16*)ws;
    u16*   z2h  = (u16*)ws;  ws += ROWB_H;
    u8*    k8   = (u8*)ws;
    u8*    z28  = (u8*)ws;   ws += ROWB_8;
    // xh/x8 (dead after spmv step 1) overlaid with z3h/z38
    u16*   xh   = (u16*)ws;
    u16*   z3h  = (u16*)ws;  ws += ROWB_H;
    u8*    x8   = (u8*)ws;
    u8*    z38  = (u8*)ws;   ws += ROWB_8;
    // evals16 (dead after finalize) overlaid with z18
    u16*   evals16 = (u16*)ws;
    u8*    z18  = (u8*)ws;   ws += (size_t)E * HEADS * 2;   // 6.4 MB
    u16*   z1h  = (u16*)ws;  ws += ROWB_H;
    float* nsum = (float*)ws; ws += (size_t)N * HEADS * 4;
    int*   deg  = (int*)ws;   ws += (size_t)N * 4;
    int*   off  = (int*)ws;   ws += ((size_t)(N + 1) * 4 + 255) & ~255ull;
    int*   bcur = (int*)ws;   ws += ((size_t)NBUCK * 4 + 255) & ~255ull;
    int*   part = (int*)ws;   ws += 256;
    u32*   epack = (u32*)ws;  ws += (size_t)E * 4;   // dst-only CSR, then packed
    u32*   tmp   = (u32*)ws;  ws += (size_t)E * 4;   // bucket-grouped edges
    u16*   Wqt   = (u16*)ws;  ws += (size_t)128 * 128 * 2;
    u16*   Wkt   = (u16*)ws;  ws += (size_t)128 * 128 * 2;

    // zero nsum + deg (contiguous)
    hipMemsetAsync(nsum, 0, (size_t)N * HEADS * 4 + (size_t)N * 4, stream);

    // W -> bf16 transposed
    wprep<<<128, 256, 0, stream>>>(Wq, Wk, Wqt, Wkt);

    // Q/K projections via MFMA (LDS-staged coalesced stores, mat-split grid)
    gemm_qk_mfma<<<dim3((N + 63) / 64, 2), 256, 0, stream>>>(
        x, Wqt, bq, Wkt, bk, qb, k8, xh, x8, N);

    // degree histogram (by src)
    hist_kernel<<<E / 256, 256, 0, stream>>>(ei, deg);

    // CSR offsets: two-level scan (+ bucket cursors)
    const int nb = (N + 1023) / 1024;
    scan1<<<nb, 1024, 0, stream>>>(deg, off, part, N);
    scan2<<<1, 64, 0, stream>>>(part, off + N, nb);
    scan3<<<nb, 1024, 0, stream>>>(off, bcur, part, N);

    // two-phase binned CSR fill
    bin_edges<<<(E + CHUNK - 1) / CHUNK, 256, 0, stream>>>(ei, bcur, tmp);
    place_edges<<<NBUCK, 256, 0, stream>>>(tmp, off, epack, N);

    // CSR-ordered scores (fp8 k gathers, pipelined indices) -> segment sums
    score_csr<<<(N * 64 + 255) / 256, 256, 0, stream>>>(
        qb, k8, off, epack, evals16, nsum, N);

    // attention mean, packed in place
    finalize_kernel<<<E / 256, 256, 0, stream>>>(evals16, nsum, epack);

    // 4 Euler steps: fp16 master chain + fp8 gather copies (pipelined)
    const int sg = (N * 64 + 255) / 256;
    spmv_h8<0><<<sg, 256, 0, stream>>>(xh,  x8,  z1h, z18, nullptr, off, epack, N);
    spmv_h8<0><<<sg, 256, 0, stream>>>(z1h, z18, z2h, z28, nullptr, off, epack, N);
    spmv_h8<0><<<sg, 256, 0, stream>>>(z2h, z28, z3h, z38, nullptr, off, epack, N);
    spmv_h8<1><<<sg, 256, 0, stream>>>(z3h, z38, nullptr, nullptr, out, off, epack, N);
}

// Round 17
// 241.670 us; speedup vs baseline: 1.4586x; 1.0781x over previous
//
#include <hip/hip_runtime.h>
#include <hip/hip_fp16.h>

#define NODES 50000
#define EDGES 800000
#define HID   128
#define HEADS 4
// DK = 32, scale = 1/sqrt(32)
#define SCORE_SCALE 0.17677669529663687f

#define NBUCK ((NODES + 255) >> 8)   // 196 buckets of 256 src nodes
#define CHUNK 4096

typedef unsigned int       u32;
typedef unsigned short     u16;
typedef unsigned char      u8;
typedef unsigned long long u64;

typedef __attribute__((ext_vector_type(8))) short bf16x8;
typedef __attribute__((ext_vector_type(4))) float f32x4;
typedef __attribute__((ext_vector_type(2))) float f32x2;

// round-to-nearest-even f32 -> bf16
__device__ __forceinline__ u16 f2bf(float f) {
    u32 u = __builtin_bit_cast(u32, f);
    return (u16)((u + 0x7FFFu + ((u >> 16) & 1u)) >> 16);
}
__device__ __forceinline__ float bflo(u32 u) { return __builtin_bit_cast(float, u << 16); }
__device__ __forceinline__ float bfhi(u32 u) { return __builtin_bit_cast(float, u & 0xFFFF0000u); }
// fp16 pair <-> f32 pair
__device__ __forceinline__ float2 h2f2(u32 u) {
    __half2 h = __builtin_bit_cast(__half2, u);
    return __half22float2(h);
}
__device__ __forceinline__ u32 f2h2(float a, float b) {
    __half2 h = __floats2half2_rn(a, b);
    return __builtin_bit_cast(u32, h);
}

// ---------------------------------------------------------------------------
// W prep: Wt[n][k] = bf16(W[k][n]), both 128x128. 2 matrices.
// ---------------------------------------------------------------------------
__global__ __launch_bounds__(256) void wprep(
    const float* __restrict__ Wq, const float* __restrict__ Wk,
    u16* __restrict__ Wqt, u16* __restrict__ Wkt)
{
    int e   = blockIdx.x * 256 + threadIdx.x;
    int mat = e >> 14;
    int idx = e & 16383;
    int k  = idx >> 7;
    int nn = idx & 127;
    const float* W = mat ? Wk : Wq;
    u16*        Wt = mat ? Wkt : Wqt;
    Wt[nn * 128 + k] = f2bf(W[idx]);
}

// ---------------------------------------------------------------------------
// MFMA Q/K projection. blockIdx.y = matrix (0:Q -> qb bf16, 1:K -> k8 fp8).
// r16 post-mortem: gemm pinned at 45us across 4 variants with NOTHING busy
// (VALU 8%, MFMA 2.5%, BW 1.6 TB/s, occ-doubling null) => TCP lookup-rate
// bound: each Wt B-frag load scatters 64 lanes over 16 rows = ~16 line-
// lookups/instr x 32 = 512 lookups/wave. Fix: W -> LDS once per block with
// XOR swizzle (chunk c -> c ^ ((c>>4)&7); same XOR on read; post-swizzle
// ds_read_b128 bank spread = 2-way = free). After MFMA, sW is dead and is
// reused as the output staging tile (coalesced flush, r15 pattern).
// mat0 blocks also emit xh (fp16 master) + x8 (fp8 gather copy).
// ---------------------------------------------------------------------------
__global__ __launch_bounds__(256) void gemm_qk_mfma(
    const float* __restrict__ x,
    const u16* __restrict__ Wqt, const float* __restrict__ bq,
    const u16* __restrict__ Wkt, const float* __restrict__ bk,
    u16* __restrict__ qb, u8* __restrict__ k8,
    u16* __restrict__ xh, u8* __restrict__ x8, int n)
{
    __shared__ __align__(16) u16 sW[128 * 128];   // 32 KB: swizzled W, then out-tile

    const int t  = threadIdx.x;
    const int l  = t & 63;
    const int w  = t >> 6;
    const int lr = l & 15;
    const int kg = l >> 4;
    const int mat = blockIdx.y;

    const u16* Wt = mat ? Wkt : Wqt;

    // cooperative swizzled W load: 2048 uint4 chunks, 16 chunks per row
    {
        const uint4* Wsrc = (const uint4*)Wt;
        uint4*       Wdst = (uint4*)sW;
        #pragma unroll
        for (int i = 0; i < 8; ++i) {
            int c   = i * 256 + t;
            int row = c >> 4;
            Wdst[c ^ (row & 7)] = Wsrc[c];
        }
    }

    const int row0   = blockIdx.x * 64;
    const int arow   = row0 + w * 16 + lr;
    const bool av    = (arow < n);
    const int  arowc = av ? arow : (n - 1);

    bf16x8 afrag[4];
    #pragma unroll
    for (int ks = 0; ks < 4; ++ks) {
        const float* px = x + (size_t)arowc * HID + ks * 32 + kg * 8;
        float4 p0 = *(const float4*)px;
        float4 p1 = *(const float4*)(px + 4);
        uint4 pk;
        pk.x = (u32)f2bf(p0.x) | ((u32)f2bf(p0.y) << 16);
        pk.y = (u32)f2bf(p0.z) | ((u32)f2bf(p0.w) << 16);
        pk.z = (u32)f2bf(p1.x) | ((u32)f2bf(p1.y) << 16);
        pk.w = (u32)f2bf(p1.z) | ((u32)f2bf(p1.w) << 16);
        afrag[ks] = __builtin_bit_cast(bf16x8, pk);
        if (mat == 0 && av) {
            uint4 ph;
            ph.x = f2h2(p0.x, p0.y);
            ph.y = f2h2(p0.z, p0.w);
            ph.z = f2h2(p1.x, p1.y);
            ph.w = f2h2(p1.z, p1.w);
            *(uint4*)(xh + (size_t)arow * HID + ks * 32 + kg * 8) = ph;
            u32 w0 = __builtin_amdgcn_cvt_pk_fp8_f32(p0.x, p0.y, 0u, false);
            w0     = __builtin_amdgcn_cvt_pk_fp8_f32(p0.z, p0.w, w0, true);
            u32 w1 = __builtin_amdgcn_cvt_pk_fp8_f32(p1.x, p1.y, 0u, false);
            w1     = __builtin_amdgcn_cvt_pk_fp8_f32(p1.z, p1.w, w1, true);
            uint2 pv; pv.x = w0; pv.y = w1;
            *(uint2*)(x8 + (size_t)arow * HID + ks * 32 + kg * 8) = pv;
        }
    }

    __syncthreads();   // sW (swizzled W) ready

    const float* bias = mat ? bk : bq;
    f32x4 accs[8];
    #pragma unroll
    for (int cb = 0; cb < 8; ++cb) {
        float bc = bias[cb * 16 + lr];
        f32x4 acc = {bc, bc, bc, bc};
        const int row = cb * 16 + lr;
        #pragma unroll
        for (int ks = 0; ks < 4; ++ks) {
            int ch = (row << 4) + ks * 4 + kg;
            bf16x8 bfrag = __builtin_bit_cast(bf16x8,
                ((const uint4*)sW)[ch ^ (row & 7)]);
            acc = __builtin_amdgcn_mfma_f32_16x16x32_bf16(afrag[ks], bfrag, acc, 0, 0, 0);
        }
        accs[cb] = acc;
    }

    __syncthreads();   // all sW reads done -> reuse as output tile

    #pragma unroll
    for (int cb = 0; cb < 8; ++cb) {
        #pragma unroll
        for (int reg = 0; reg < 4; ++reg) {
            int lrow = w * 16 + kg * 4 + reg;        // tile row 0..63
            if (mat == 0) {
                sW[lrow * 128 + cb * 16 + lr] = f2bf(accs[cb][reg]);
            } else {
                u32 p8 = __builtin_amdgcn_cvt_pk_fp8_f32(accs[cb][reg], 0.f, 0u, false);
                ((u8*)sW)[lrow * 128 + cb * 16 + lr] = (u8)(p8 & 0xFFu);
            }
        }
    }
    __syncthreads();

    if (mat == 0) {
        #pragma unroll
        for (int i = 0; i < 4; ++i) {
            int idx = i * 256 + t;
            int row = idx >> 4;
            int ch  = idx & 15;
            if (row0 + row < n)
                *(uint4*)(qb + (size_t)(row0 + row) * HID + ch * 8) =
                    *(const uint4*)&sW[row * 128 + ch * 8];
        }
    } else {
        #pragma unroll
        for (int i = 0; i < 2; ++i) {
            int idx = i * 256 + t;
            int row = idx >> 3;
            int ch  = idx & 7;
            if (row0 + row < n)
                *(uint4*)(k8 + (size_t)(row0 + row) * HID + ch * 16) =
                    *(const uint4*)((const u8*)sW + row * 128 + ch * 16);
        }
    }
}

// ---------------------------------------------------------------------------
// out-degree histogram over src
// ---------------------------------------------------------------------------
__global__ __launch_bounds__(256) void hist_kernel(
    const int* __restrict__ ei, int* __restrict__ deg)
{
    int i = blockIdx.x * 256 + threadIdx.x;
    if (i < EDGES) atomicAdd(&deg[ei[i]], 1);
}

// ---------------------------------------------------------------------------
// two-level exclusive scan of deg -> off; also emits bucket cursors
// ---------------------------------------------------------------------------
__global__ __launch_bounds__(1024) void scan1(
    const int* __restrict__ deg, int* __restrict__ off,
    int* __restrict__ part, int n)
{
    __shared__ int sd[1024];
    int t = threadIdx.x, i = blockIdx.x * 1024 + t;
    int v = (i < n) ? deg[i] : 0;
    sd[t] = v;
    __syncthreads();
    #pragma unroll
    for (int o = 1; o < 1024; o <<= 1) {
        int a = (t >= o) ? sd[t - o] : 0;
        __syncthreads();
        sd[t] += a;
        __syncthreads();
    }
    if (i < n) off[i] = sd[t] - v;
    if (t == 1023) part[blockIdx.x] = sd[1023];
}

__global__ __launch_bounds__(64) void scan2(int* __restrict__ part,
                                            int* __restrict__ off_n, int nb)
{
    int t = threadIdx.x;
    int v = (t < nb) ? part[t] : 0;
    int orig = v;
    #pragma unroll
    for (int o = 1; o < 64; o <<= 1) {
        int a = __shfl_up(v, o);
        if (t >= o) v += a;
    }
    if (t < nb) part[t] = v - orig;
    if (t == 63) *off_n = v;
}

__global__ __launch_bounds__(1024) void scan3(
    int* __restrict__ off, int* __restrict__ bcur,
    const int* __restrict__ part, int n)
{
    int i = blockIdx.x * 1024 + threadIdx.x;
    if (i < n) {
        int o = off[i] + part[blockIdx.x];
        off[i] = o;
        if ((i & 255) == 0) bcur[i >> 8] = o;   // bucket base cursor
    }
}

// ---------------------------------------------------------------------------
// Phase 1: bin edges by bucket (src>>8) into tmp, bucket-contiguous.
// ---------------------------------------------------------------------------
__global__ __launch_bounds__(256) void bin_edges(
    const int* __restrict__ ei, int* __restrict__ bcur, u32* __restrict__ tmp)
{
    __shared__ u32 buf[CHUNK];
    __shared__ int hist[NBUCK];
    __shared__ int lcur[NBUCK];

    const int t  = threadIdx.x;
    const int e0 = blockIdx.x * CHUNK;
    const int e1 = (e0 + CHUNK < EDGES) ? e0 + CHUNK : EDGES;
    const int cnt = e1 - e0;

    for (int b = t; b < NBUCK; b += 256) hist[b] = 0;
    __syncthreads();

    for (int i = t; i < cnt; i += 256) {
        int src = ei[e0 + i];
        int dst = ei[EDGES + e0 + i];
        buf[i] = (u32)dst | ((u32)(src & 255) << 16) | ((u32)(src >> 8) << 24);
        atomicAdd(&hist[src >> 8], 1);
    }
    __syncthreads();

    for (int b = t; b < NBUCK; b += 256) {
        int h = hist[b];
        lcur[b] = h ? atomicAdd(&bcur[b], h) : 0;
    }
    __syncthreads();

    for (int i = t; i < cnt; i += 256) {
        u32 pk  = buf[i];
        int b   = pk >> 24;
        int pos = atomicAdd(&lcur[b], 1);
        tmp[pos] = pk & 0x00FFFFFFu;          // srcLocal<<16 | dst
    }
}

// ---------------------------------------------------------------------------
// Phase 2: exact CSR placement within each bucket (LDS cursors, local window)
// ---------------------------------------------------------------------------
__global__ __launch_bounds__(256) void place_edges(
    const u32* __restrict__ tmp, const int* __restrict__ off,
    u32* __restrict__ epack, int n)
{
    __shared__ int lcur[256];
    const int t     = threadIdx.x;
    const int nbase = blockIdx.x << 8;
    const int nend  = (nbase + 256 < n) ? nbase + 256 : n;

    if (nbase + t < nend) lcur[t] = off[nbase + t];
    __syncthreads();

    const int s0 = off[nbase];
    const int s1 = off[nend];
    for (int i = s0 + t; i < s1; i += 256) {
        u32 pk    = tmp[i];
        int local = pk >> 16;
        int pos   = atomicAdd(&lcur[local], 1);
        epack[pos] = pk & 0xFFFFu;            // dst only (att packed later)
    }
}

// ---------------------------------------------------------------------------
// CSR-ordered scores, software-pipelined index stream (r16). Wave per src
// node, 4 groups x 16 lanes; q[src] bf16 loaded once; k gathered as fp8.
// ---------------------------------------------------------------------------
__global__ __launch_bounds__(256) void score_csr(
    const u16* __restrict__ qb, const u8* __restrict__ k8,
    const int* __restrict__ off, const u32* __restrict__ ccol,
    u16* __restrict__ evals16, float* __restrict__ nsum, int n)
{
    const int wv   = (blockIdx.x * 256 + threadIdx.x) >> 6;   // src node
    const int lane = threadIdx.x & 63;
    const int l16  = lane & 15;
    const int grp  = lane >> 4;
    if (wv >= n) return;

    const int beg = off[wv];
    const int end = off[wv + 1];
    if (beg >= end) return;

    uint4 qv = *(const uint4*)(qb + (size_t)wv * HID + l16 * 8);

    u32 d[4];
    #pragma unroll
    for (int u = 0; u < 4; ++u) {
        int e  = beg + grp + u * 4;
        int ec = (e < end) ? e : (end - 1);
        d[u] = ccol[ec];
    }

    for (int j = beg; j < end; j += 16) {
        u64 kv[4];
        #pragma unroll
        for (int u = 0; u < 4; ++u)
            kv[u] = *(const u64*)(k8 + (size_t)d[u] * HID + l16 * 8);

        u32 dn[4];
        #pragma unroll
        for (int u = 0; u < 4; ++u) {
            int e  = j + 16 + grp + u * 4;
            int ec = (e < end) ? e : (end - 1);
            dn[u] = ccol[ec];
        }

        #pragma unroll
        for (int u = 0; u < 4; ++u) {
            int e = j + grp + u * 4;
            u32 klo = (u32)kv[u], khi = (u32)(kv[u] >> 32);
            f32x2 a = __builtin_amdgcn_cvt_pk_f32_fp8(klo, false);
            f32x2 b = __builtin_amdgcn_cvt_pk_f32_fp8(klo, true);
            f32x2 c = __builtin_amdgcn_cvt_pk_f32_fp8(khi, false);
            f32x2 dd= __builtin_amdgcn_cvt_pk_f32_fp8(khi, true);
            float p = bflo(qv.x) * a.x + bfhi(qv.x) * a.y
                    + bflo(qv.y) * b.x + bfhi(qv.y) * b.y
                    + bflo(qv.z) * c.x + bfhi(qv.z) * c.y
                    + bflo(qv.w) * dd.x + bfhi(qv.w) * dd.y;
            p += __shfl_xor(p, 1);
            p += __shfl_xor(p, 2);
            if (e < end && (l16 & 3) == 0) {
                int head = l16 >> 2;
                float ev = __expf(p * SCORE_SCALE);
                evals16[(size_t)e * HEADS + head] = f2bf(ev);
                atomicAdd(&nsum[(size_t)d[u] * HEADS + head], ev);
            }
        }

        #pragma unroll
        for (int u = 0; u < 4; ++u) d[u] = dn[u];
    }
}

// ---------------------------------------------------------------------------
// head-mean attention; packs epack[pos] = dst | bf16(att)<<16 IN PLACE.
// ---------------------------------------------------------------------------
__global__ __launch_bounds__(256) void finalize_kernel(
    const u16* __restrict__ evals16, const float* __restrict__ nsum,
    u32* __restrict__ epack)
{
    int pos = blockIdx.x * 256 + threadIdx.x;
    if (pos >= EDGES) return;
    u32 dst = epack[pos];
    u64 ev8 = *(const u64*)(evals16 + (size_t)pos * HEADS);
    u32 lo = (u32)ev8, hi = (u32)(ev8 >> 32);
    float4 sv = *(const float4*)(nsum + (size_t)dst * HEADS);
    float am = 0.25f * (bflo(lo) / (sv.x + 1e-16f) + bfhi(lo) / (sv.y + 1e-16f) +
                        bflo(hi) / (sv.z + 1e-16f) + bfhi(hi) / (sv.w + 1e-16f));
    epack[pos] = dst | ((u32)f2bf(am) << 16);
}

// ---------------------------------------------------------------------------
// SCALARIZED + SOFTWARE-PIPELINED Euler step with fp8 gathers (r16).
// Master state fp16; gathered copy fp8 (128B row). Final step writes f32.
// ---------------------------------------------------------------------------
template<int FINAL>
__global__ __launch_bounds__(256) void spmv_h8(
    const u16* __restrict__ inh, const u8* __restrict__ in8,
    u16* __restrict__ outh, u8* __restrict__ out8,
    float* __restrict__ outf,
    const int* __restrict__ off, const u32* __restrict__ epack, int n)
{
    const int w    = (blockIdx.x * 256 + threadIdx.x) >> 6;
    const int lane = threadIdx.x & 63;
    if (w >= n) return;

    const int beg = __builtin_amdgcn_readfirstlane(off[w]);
    const int end = __builtin_amdgcn_readfirstlane(off[w + 1]);

    const u16* in8w = (const u16*)in8;         // 64 fp8-pairs per 128-dim row

    float ax = 0.f, ay = 0.f;
    int j = beg;

    if (j + 8 <= end) {
        u32 eA[8];
        #pragma unroll
        for (int u = 0; u < 8; ++u) eA[u] = epack[j + u];       // uniform -> SGPR

        for (; j + 16 <= end; j += 8) {
            u32 s[8];
            #pragma unroll
            for (int u = 0; u < 8; ++u)
                s[u] = in8w[(size_t)(eA[u] & 0xFFFFu) * 64 + lane];

            u32 eB[8];
            #pragma unroll
            for (int u = 0; u < 8; ++u) eB[u] = epack[j + 8 + u];

            #pragma unroll
            for (int u = 0; u < 8; ++u) {
                float vv = bfhi(eA[u]);
                f32x2 sv = __builtin_amdgcn_cvt_pk_f32_fp8(s[u], false);
                ax += vv * sv.x;
                ay += vv * sv.y;
            }
            #pragma unroll
            for (int u = 0; u < 8; ++u) eA[u] = eB[u];
        }

        u32 s[8];
        #pragma unroll
        for (int u = 0; u < 8; ++u)
            s[u] = in8w[(size_t)(eA[u] & 0xFFFFu) * 64 + lane];
        #pragma unroll
        for (int u = 0; u < 8; ++u) {
            float vv = bfhi(eA[u]);
            f32x2 sv = __builtin_amdgcn_cvt_pk_f32_fp8(s[u], false);
            ax += vv * sv.x;
            ay += vv * sv.y;
        }
        j += 8;
    }

    for (; j + 4 <= end; j += 4) {
        u32 e[4], s[4];
        #pragma unroll
        for (int u = 0; u < 4; ++u) e[u] = epack[j + u];
        #pragma unroll
        for (int u = 0; u < 4; ++u)
            s[u] = in8w[(size_t)(e[u] & 0xFFFFu) * 64 + lane];
        #pragma unroll
        for (int u = 0; u < 4; ++u) {
            float vv = bfhi(e[u]);
            f32x2 sv = __builtin_amdgcn_cvt_pk_f32_fp8(s[u], false);
            ax += vv * sv.x;
            ay += vv * sv.y;
        }
    }
    for (; j < end; ++j) {
        u32 e = epack[j];
        u32 s = in8w[(size_t)(e & 0xFFFFu) * 64 + lane];
        float vv = bfhi(e);
        f32x2 sv = __builtin_amdgcn_cvt_pk_f32_fp8(s, false);
        ax += vv * sv.x;
        ay += vv * sv.y;
    }

    // own row from fp16 MASTER (full precision path)
    u32 zi = *(const u32*)(inh + (size_t)w * HID + lane * 2);
    float2 xi = h2f2(zi);
    const float ox = 0.75f * xi.x + 0.25f * ax;
    const float oy = 0.75f * xi.y + 0.25f * ay;
    if (FINAL) {
        float2 o; o.x = ox; o.y = oy;
        *(float2*)(outf + (size_t)w * HID + lane * 2) = o;
    } else {
        *(u32*)(outh + (size_t)w * HID + lane * 2) = f2h2(ox, oy);
        u32 p8 = __builtin_amdgcn_cvt_pk_fp8_f32(ox, oy, 0u, false);
        ((u16*)out8)[(size_t)w * 64 + lane] = (u16)(p8 & 0xFFFFu);
    }
}

// ---------------------------------------------------------------------------
extern "C" void kernel_launch(void* const* d_in, const int* in_sizes, int n_in,
                              void* d_out, int out_size, void* d_ws, size_t ws_size,
                              hipStream_t stream)
{
    (void)in_sizes; (void)n_in; (void)out_size; (void)ws_size;

    const float* x  = (const float*)d_in[0];
    const float* Wq = (const float*)d_in[1];
    const float* bq = (const float*)d_in[2];
    const float* Wk = (const float*)d_in[3];
    const float* bk = (const float*)d_in[4];
    const int*   ei = (const int*)d_in[5];
    float* out = (float*)d_out;

    const int N = NODES, E = EDGES;
    const size_t ROWB_H = (size_t)N * HID * 2;   // 12.8 MB fp16 state
    const size_t ROWB_8 = (size_t)N * HID;       //  6.4 MB fp8 state

    char* ws = (char*)d_ws;
    // qb (dead after score) overlaid with z2h; k8 (dead after score) with z28
    u16*   qb   = (u16*)ws;
    u16*   z2h  = (u16*)ws;  ws += ROWB_H;
    u8*    k8   = (u8*)ws;
    u8*    z28  = (u8*)ws;   ws += ROWB_8;
    // xh/x8 (dead after spmv step 1) overlaid with z3h/z38
    u16*   xh   = (u16*)ws;
    u16*   z3h  = (u16*)ws;  ws += ROWB_H;
    u8*    x8   = (u8*)ws;
    u8*    z38  = (u8*)ws;   ws += ROWB_8;
    // evals16 (dead after finalize) overlaid with z18
    u16*   evals16 = (u16*)ws;
    u8*    z18  = (u8*)ws;   ws += (size_t)E * HEADS * 2;   // 6.4 MB
    u16*   z1h  = (u16*)ws;  ws += ROWB_H;
    float* nsum = (float*)ws; ws += (size_t)N * HEADS * 4;
    int*   deg  = (int*)ws;   ws += (size_t)N * 4;
    int*   off  = (int*)ws;   ws += ((size_t)(N + 1) * 4 + 255) & ~255ull;
    int*   bcur = (int*)ws;   ws += ((size_t)NBUCK * 4 + 255) & ~255ull;
    int*   part = (int*)ws;   ws += 256;
    u32*   epack = (u32*)ws;  ws += (size_t)E * 4;   // dst-only CSR, then packed
    u32*   tmp   = (u32*)ws;  ws += (size_t)E * 4;   // bucket-grouped edges
    u16*   Wqt   = (u16*)ws;  ws += (size_t)128 * 128 * 2;
    u16*   Wkt   = (u16*)ws;  ws += (size_t)128 * 128 * 2;

    // zero nsum + deg (contiguous)
    hipMemsetAsync(nsum, 0, (size_t)N * HEADS * 4 + (size_t)N * 4, stream);

    // W -> bf16 transposed
    wprep<<<128, 256, 0, stream>>>(Wq, Wk, Wqt, Wkt);

    // Q/K projections via MFMA (W in swizzled LDS, coalesced flush)
    gemm_qk_mfma<<<dim3((N + 63) / 64, 2), 256, 0, stream>>>(
        x, Wqt, bq, Wkt, bk, qb, k8, xh, x8, N);

    // degree histogram (by src)
    hist_kernel<<<E / 256, 256, 0, stream>>>(ei, deg);

    // CSR offsets: two-level scan (+ bucket cursors)
    const int nb = (N + 1023) / 1024;
    scan1<<<nb, 1024, 0, stream>>>(deg, off, part, N);
    scan2<<<1, 64, 0, stream>>>(part, off + N, nb);
    scan3<<<nb, 1024, 0, stream>>>(off, bcur, part, N);

    // two-phase binned CSR fill
    bin_edges<<<(E + CHUNK - 1) / CHUNK, 256, 0, stream>>>(ei, bcur, tmp);
    place_edges<<<NBUCK, 256, 0, stream>>>(tmp, off, epack, N);

    // CSR-ordered scores (fp8 k gathers, pipelined indices) -> segment sums
    score_csr<<<(N * 64 + 255) / 256, 256, 0, stream>>>(
        qb, k8, off, epack, evals16, nsum, N);

    // attention mean, packed in place
    finalize_kernel<<<E / 256, 256, 0, stream>>>(evals16, nsum, epack);

    // 4 Euler steps: fp16 master chain + fp8 gather copies (pipelined)
    const int sg = (N * 64 + 255) / 256;
    spmv_h8<0><<<sg, 256, 0, stream>>>(xh,  x8,  z1h, z18, nullptr, off, epack, N);
    spmv_h8<0><<<sg, 256, 0, stream>>>(z1h, z18, z2h, z28, nullptr, off, epack, N);
    spmv_h8<0><<<sg, 256, 0, stream>>>(z2h, z28, z3h, z38, nullptr, off, epack, N);
    spmv_h8<1><<<sg, 256, 0, stream>>>(z3h, z38, nullptr, nullptr, out, off, epack, N);
}